// Round 1
// baseline (1021.747 us; speedup 1.0000x reference)
//
#include <hip/hip_runtime.h>
#include <stdint.h>

// ---------- sizes ----------
// img (8,160,240,3) -> conv1 6x6 -> (8,155,235,32) -> pool -> (8,77,117,32)
// -> conv2 3x3 -> (8,75,115,64) -> pool -> (8,37,57,64)
// -> conv3 3x3 -> (8,35,55,128) -> flatten 246400 -> dense 256 -> dense 38400
// -> transform -> pred (8,40,60,16); NMS -> keep (8,3,4800)

static __device__ __forceinline__ float sigmoidf_(float x) {
  return 1.0f / (1.0f + expf(-x));
}

// ---------------- conv1: 6x6x3 -> 32, thread = one pixel, all 32 ch ----------------
__global__ __launch_bounds__(256) void k_conv1(const float* __restrict__ in,
    const float* __restrict__ w, const float* __restrict__ bias, float* __restrict__ out) {
  int t = blockIdx.x * 256 + threadIdx.x;
  const int NP = 8 * 155 * 235;
  if (t >= NP) return;
  int x = t % 235, y = (t / 235) % 155, n = t / (235 * 155);
  float acc[32];
#pragma unroll
  for (int o = 0; o < 32; o++) acc[o] = bias[o];
  const float* ip = in + ((size_t)(n * 160 + y) * 240 + x) * 3;
#pragma unroll 1
  for (int ky = 0; ky < 6; ky++) {
    const float* rp = ip + ky * (240 * 3);
#pragma unroll
    for (int kx = 0; kx < 6; kx++) {
      float i0 = rp[kx * 3 + 0], i1 = rp[kx * 3 + 1], i2 = rp[kx * 3 + 2];
      const float* wp = w + ((ky * 6 + kx) * 3) * 32;
#pragma unroll
      for (int o = 0; o < 32; o++) acc[o] = fmaf(i0, wp[o], acc[o]);
#pragma unroll
      for (int o = 0; o < 32; o++) acc[o] = fmaf(i1, wp[32 + o], acc[o]);
#pragma unroll
      for (int o = 0; o < 32; o++) acc[o] = fmaf(i2, wp[64 + o], acc[o]);
    }
  }
  float4* op = (float4*)(out + (size_t)t * 32);
#pragma unroll
  for (int q = 0; q < 8; q++) {
    float4 v;
    v.x = fmaxf(acc[q * 4 + 0], 0.f);
    v.y = fmaxf(acc[q * 4 + 1], 0.f);
    v.z = fmaxf(acc[q * 4 + 2], 0.f);
    v.w = fmaxf(acc[q * 4 + 3], 0.f);
    op[q] = v;
  }
}

// ---------------- 2x2 max pool, VALID ----------------
__global__ __launch_bounds__(256) void k_pool(const float* __restrict__ in, float* __restrict__ out,
    int N, int IH, int IW, int OH, int OW, int C) {
  int t = blockIdx.x * 256 + threadIdx.x;
  int total = N * OH * OW * C;
  if (t >= total) return;
  int c = t % C;
  int x = (t / C) % OW;
  int y = (t / (C * OW)) % OH;
  int n = t / (C * OW * OH);
  const float* p = in + ((size_t)(n * IH + y * 2) * IW + x * 2) * C + c;
  float a = fmaxf(p[0], p[C]);
  float b = fmaxf(p[(size_t)IW * C], p[(size_t)IW * C + C]);
  out[t] = fmaxf(a, b);
}

// ---------------- conv2: 3x3x32 -> 64, thread = pixel x 16-ch group (4 groups) --------
__global__ __launch_bounds__(256) void k_conv2(const float* __restrict__ in,
    const float* __restrict__ w, const float* __restrict__ bias, float* __restrict__ out) {
  int t = blockIdx.x * 256 + threadIdx.x;
  const int NP = 8 * 75 * 115 * 4;
  if (t >= NP) return;
  int g = t & 3;
  int pix = t >> 2;
  int x = pix % 115, y = (pix / 115) % 75, n = pix / (115 * 75);
  float acc[16];
  const float* bp = bias + g * 16;
#pragma unroll
  for (int o = 0; o < 16; o++) acc[o] = bp[o];
  const float* ip = in + ((size_t)(n * 77 + y) * 117 + x) * 32;
#pragma unroll 1
  for (int ky = 0; ky < 3; ky++) {
#pragma unroll 1
    for (int kx = 0; kx < 3; kx++) {
      const float4* iv = (const float4*)(ip + (ky * 117 + kx) * 32);
      const float* wp = w + ((ky * 3 + kx) * 32) * 64 + g * 16;
#pragma unroll
      for (int c4 = 0; c4 < 8; c4++) {
        float4 v = iv[c4];
#pragma unroll
        for (int o = 0; o < 16; o++) acc[o] = fmaf(v.x, wp[(c4 * 4 + 0) * 64 + o], acc[o]);
#pragma unroll
        for (int o = 0; o < 16; o++) acc[o] = fmaf(v.y, wp[(c4 * 4 + 1) * 64 + o], acc[o]);
#pragma unroll
        for (int o = 0; o < 16; o++) acc[o] = fmaf(v.z, wp[(c4 * 4 + 2) * 64 + o], acc[o]);
#pragma unroll
        for (int o = 0; o < 16; o++) acc[o] = fmaf(v.w, wp[(c4 * 4 + 3) * 64 + o], acc[o]);
      }
    }
  }
  float4* op = (float4*)(out + (size_t)pix * 64 + g * 16);
#pragma unroll
  for (int q = 0; q < 4; q++) {
    float4 v;
    v.x = fmaxf(acc[q * 4 + 0], 0.f);
    v.y = fmaxf(acc[q * 4 + 1], 0.f);
    v.z = fmaxf(acc[q * 4 + 2], 0.f);
    v.w = fmaxf(acc[q * 4 + 3], 0.f);
    op[q] = v;
  }
}

// ---------------- conv3: 3x3x64 -> 128, thread = pixel x 16-ch group (8 groups) -------
__global__ __launch_bounds__(256) void k_conv3(const float* __restrict__ in,
    const float* __restrict__ w, const float* __restrict__ bias, float* __restrict__ out) {
  int t = blockIdx.x * 256 + threadIdx.x;
  const int NP = 8 * 35 * 55 * 8;
  if (t >= NP) return;
  int g = t & 7;
  int pix = t >> 3;
  int x = pix % 55, y = (pix / 55) % 35, n = pix / (55 * 35);
  float acc[16];
  const float* bp = bias + g * 16;
#pragma unroll
  for (int o = 0; o < 16; o++) acc[o] = bp[o];
  const float* ip = in + ((size_t)(n * 37 + y) * 57 + x) * 64;
#pragma unroll 1
  for (int ky = 0; ky < 3; ky++) {
#pragma unroll 1
    for (int kx = 0; kx < 3; kx++) {
      const float4* iv = (const float4*)(ip + (ky * 57 + kx) * 64);
      const float* wp = w + ((ky * 3 + kx) * 64) * 128 + g * 16;
#pragma unroll 4
      for (int c4 = 0; c4 < 16; c4++) {
        float4 v = iv[c4];
#pragma unroll
        for (int o = 0; o < 16; o++) acc[o] = fmaf(v.x, wp[(c4 * 4 + 0) * 128 + o], acc[o]);
#pragma unroll
        for (int o = 0; o < 16; o++) acc[o] = fmaf(v.y, wp[(c4 * 4 + 1) * 128 + o], acc[o]);
#pragma unroll
        for (int o = 0; o < 16; o++) acc[o] = fmaf(v.z, wp[(c4 * 4 + 2) * 128 + o], acc[o]);
#pragma unroll
        for (int o = 0; o < 16; o++) acc[o] = fmaf(v.w, wp[(c4 * 4 + 3) * 128 + o], acc[o]);
      }
    }
  }
  float4* op = (float4*)(out + (size_t)pix * 128 + g * 16);
#pragma unroll
  for (int q = 0; q < 4; q++) {
    float4 v;
    v.x = fmaxf(acc[q * 4 + 0], 0.f);
    v.y = fmaxf(acc[q * 4 + 1], 0.f);
    v.z = fmaxf(acc[q * 4 + 2], 0.f);
    v.w = fmaxf(acc[q * 4 + 3], 0.f);
    op[q] = v;
  }
}

// ---------------- transpose a3 (8,246400) -> a3t (246400,8) ----------------
__global__ __launch_bounds__(256) void k_transpose_a3(const float* __restrict__ a3,
                                                      float* __restrict__ a3t) {
  int k = blockIdx.x * 256 + threadIdx.x;
  if (k >= 246400) return;
#pragma unroll
  for (int n = 0; n < 8; n++) a3t[(size_t)k * 8 + n] = a3[(size_t)n * 246400 + k];
}

// ---------------- dense1 split-K partials: (8,246400) @ (246400,256) ----------------
__global__ __launch_bounds__(256) void k_dense1(const float* __restrict__ a3t,
    const float* __restrict__ wd1, float* __restrict__ part) {
  int c = blockIdx.x;       // K-chunk, 963 chunks of 256
  int j = threadIdx.x;      // output column
  int k0 = c * 256;
  int kn = min(256, 246400 - k0);
  float acc[8];
#pragma unroll
  for (int n = 0; n < 8; n++) acc[n] = 0.f;
  const float* wp = wd1 + (size_t)k0 * 256 + j;
  const float* xp = a3t + (size_t)k0 * 8;
#pragma unroll 8
  for (int kk = 0; kk < kn; kk++) {
    float wv = wp[(size_t)kk * 256];
#pragma unroll
    for (int n = 0; n < 8; n++) acc[n] = fmaf(xp[kk * 8 + n], wv, acc[n]);
  }
  float* pp = part + (size_t)c * 2048 + j;
#pragma unroll
  for (int n = 0; n < 8; n++) pp[n * 256] = acc[n];
}

__global__ __launch_bounds__(256) void k_reduce1(const float* __restrict__ part,
    const float* __restrict__ bd1, float* __restrict__ d1t) {
  int t = blockIdx.x * 256 + threadIdx.x;  // 0..2047
  if (t >= 2048) return;
  float s = 0.f;
  for (int c = 0; c < 963; c++) s += part[(size_t)c * 2048 + t];
  int n = t >> 8, j = t & 255;
  float v = s + bd1[j];
  d1t[j * 8 + n] = fmaxf(v, 0.f);   // ReLU; store transposed (256,8)
}

// ---------------- dense2 split-K partials: (8,256) @ (256,38400) ----------------
__global__ __launch_bounds__(256) void k_dense2(const float* __restrict__ d1t,
    const float* __restrict__ wd2, float* __restrict__ part) {
  int jb = blockIdx.x;   // 150
  int ks = blockIdx.y;   // 2
  int j = jb * 256 + threadIdx.x;
  float acc[8];
#pragma unroll
  for (int n = 0; n < 8; n++) acc[n] = 0.f;
  const float* xp = d1t + ks * 128 * 8;
  const float* wp = wd2 + (size_t)ks * 128 * 38400 + j;
#pragma unroll 8
  for (int kk = 0; kk < 128; kk++) {
    float wv = wp[(size_t)kk * 38400];
#pragma unroll
    for (int n = 0; n < 8; n++) acc[n] = fmaf(xp[kk * 8 + n], wv, acc[n]);
  }
  float* pp = part + (size_t)ks * 8 * 38400 + j;
#pragma unroll
  for (int n = 0; n < 8; n++) pp[(size_t)n * 38400] = acc[n];
}

__global__ __launch_bounds__(256) void k_reduce2(const float* __restrict__ part,
    const float* __restrict__ bd2, float* __restrict__ d2) {
  int t = blockIdx.x * 256 + threadIdx.x;
  if (t >= 8 * 38400) return;
  int n = t / 38400, j = t - n * 38400;
  d2[t] = part[(size_t)n * 38400 + j] + part[(size_t)(8 + n) * 38400 + j] + bd2[j];
}

// ---------------- predict_transform + per-box NMS precompute ----------------
__global__ __launch_bounds__(256) void k_transform(const float* __restrict__ d2,
    float* __restrict__ pred, float* __restrict__ boxd) {
  int t = blockIdx.x * 256 + threadIdx.x;  // 8*2400
  if (t >= 19200) return;
  int cell = t % 2400;
  int n = t / 2400;
  float gx = (float)(cell % 60), gy = (float)(cell / 60);
  const float* p = d2 + (size_t)t * 16;
  float o[16];
  o[0] = (sigmoidf_(p[0]) + gx) * 4.0f;
  o[1] = (sigmoidf_(p[1]) + gy) * 4.0f;
  o[2] = expf(p[2]) * 60.0f * 4.0f;
  o[3] = expf(p[3]) * 30.0f * 4.0f;
  o[4] = sigmoidf_(p[4]);
  o[5] = sigmoidf_(p[5]);
  o[6] = sigmoidf_(p[6]);
  o[7] = sigmoidf_(p[7]);
  o[8] = (p[8] + gx) * 4.0f;
  o[9] = (p[9] + gy) * 4.0f;
  o[10] = expf(p[10]) * 20.0f * 4.0f;
  o[11] = expf(p[11]) * 40.0f * 4.0f;
  o[12] = p[12];
  o[13] = sigmoidf_(p[13]);
  o[14] = sigmoidf_(p[14]);
  o[15] = sigmoidf_(p[15]);
  float* op = pred + (size_t)t * 16;
#pragma unroll
  for (int q = 0; q < 16; q++) op[q] = o[q];
  // per-box derived data for NMS: x1,y1,x2,y2,area,conf,cls,pad
#pragma unroll
  for (int h = 0; h < 2; h++) {
    int b = n * 4800 + h * 2400 + cell;
    float X = o[h * 8 + 0], Y = o[h * 8 + 1], W = o[h * 8 + 2], H = o[h * 8 + 3];
    float conf = o[h * 8 + 4];
    float c0 = o[h * 8 + 5], c1 = o[h * 8 + 6], c2 = o[h * 8 + 7];
    int cls = 0; float best = c0;
    if (c1 > best) { best = c1; cls = 1; }
    if (c2 > best) { best = c2; cls = 2; }
    float x1 = X - W / 2.0f, y1 = Y - H / 2.0f;
    float x2 = X + W / 2.0f, y2 = Y + H / 2.0f;
    float area = (x2 - x1 + 1.0f) * (y2 - y1 + 1.0f);
    float* bp2 = boxd + (size_t)b * 8;
    bp2[0] = x1; bp2[1] = y1; bp2[2] = x2; bp2[3] = y2;
    bp2[4] = area; bp2[5] = conf;
    ((int*)bp2)[6] = cls; bp2[7] = 0.f;
  }
}

__global__ __launch_bounds__(256) void k_zero(float* __restrict__ keep_out, int* __restrict__ cnt) {
  int t = blockIdx.x * 256 + threadIdx.x;
  if (t < 115200) keep_out[t] = 0.f;
  if (t < 24) cnt[t] = 0;
}

// ---------------- NMS: one block per (image, class) ----------------
__global__ __launch_bounds__(256) void k_nms(const float* __restrict__ boxd,
    int* __restrict__ cnt, float* __restrict__ keep_out) {
  __shared__ unsigned long long key[8192];
  int bid = blockIdx.x;  // 0..23
  int n = bid / 3, c = bid - n * 3;
  int tid = threadIdx.x;
  const float* bd = boxd + (size_t)n * 4800 * 8;
  int* myc = cnt + bid;

  // compact valid boxes of this class; key = (~sortable(score) << 32) | idx
  for (int p = tid; p < 4800; p += 256) {
    const float* bp = bd + (size_t)p * 8;
    float conf = bp[5];
    int cls = ((const int*)bp)[6];
    if (conf > 0.5f && cls == c) {
      unsigned slot = (unsigned)atomicAdd(myc, 1);
      unsigned u = __float_as_uint(conf);
      unsigned asc = (u & 0x80000000u) ? ~u : (u | 0x80000000u);
      key[slot] = (((unsigned long long)(~asc)) << 32) | (unsigned)p;
    }
  }
  __syncthreads();
  int V = atomicAdd(myc, 0);
  if (V == 0) return;
  int Vp2 = 1;
  while (Vp2 < V) Vp2 <<= 1;
  for (int s = V + tid; s < Vp2; s += 256) key[s] = ~0ull;

  // bitonic sort ascending over Vp2 entries -> score desc, idx asc
  for (int k = 2; k <= Vp2; k <<= 1) {
    for (int j = k >> 1; j > 0; j >>= 1) {
      __syncthreads();
      int jm = j - 1;
      for (int t2 = tid; t2 < (Vp2 >> 1); t2 += 256) {
        int i = ((t2 & ~jm) << 1) | (t2 & jm);
        int q = i | j;
        bool up = ((i & k) == 0);
        unsigned long long a = key[i], b2 = key[q];
        if ((a > b2) == up) { key[i] = b2; key[q] = a; }
      }
    }
  }
  __syncthreads();
  if (tid >= 64) return;

  // single-wave greedy NMS; keep flags as per-lane register bitmasks
  int lane = tid;
  int tmax = (V + 63) >> 6;
  unsigned w0 = 0, w1 = 0, w2 = 0;
  for (int t3 = 0; t3 < tmax; ++t3) {
    int p = lane + (t3 << 6);
    if (p < V) {
      if (t3 < 32) w0 |= 1u << t3;
      else if (t3 < 64) w1 |= 1u << (t3 - 32);
      else w2 |= 1u << (t3 - 64);
    }
  }
  for (int i = 0; i < V; i++) {
    int ti = i >> 6, li = i & 63;
    unsigned wm = (ti >= 64) ? w2 : ((ti >= 32) ? w1 : w0);
    int bit = (int)((wm >> (ti & 31)) & 1u);
    int ki = __shfl(bit, li, 64);
    if (ki == 0) continue;
    const float* bi = bd + (size_t)((unsigned)(key[i] & 0xFFFFFFFFull)) * 8;
    float ax1 = bi[0], ay1 = bi[1], ax2 = bi[2], ay2 = bi[3], aa = bi[4];
    for (int t3 = 0; t3 < tmax; ++t3) {
      int p = lane + (t3 << 6);
      unsigned wm2 = (t3 >= 64) ? w2 : ((t3 >= 32) ? w1 : w0);
      unsigned mybit = (wm2 >> (t3 & 31)) & 1u;
      if (p > i && p < V && mybit) {
        const float* bj = bd + (size_t)((unsigned)(key[p] & 0xFFFFFFFFull)) * 8;
        float iw = fminf(ax2, bj[2]) - fmaxf(ax1, bj[0]) + 1.0f;
        float ih = fminf(ay2, bj[3]) - fmaxf(ay1, bj[1]) + 1.0f;
        iw = fmaxf(iw, 0.f);
        ih = fmaxf(ih, 0.f);
        float inter = iw * ih;
        float iou = inter / (aa + bj[4] - inter);
        if (iou >= 0.4f) {
          if (t3 < 32) w0 &= ~(1u << t3);
          else if (t3 < 64) w1 &= ~(1u << (t3 - 32));
          else w2 &= ~(1u << (t3 - 64));
        }
      }
    }
  }
  float* ko = keep_out + (size_t)(n * 3 + c) * 4800;
  for (int t3 = 0; t3 < tmax; ++t3) {
    int p = lane + (t3 << 6);
    if (p < V) {
      unsigned wm2 = (t3 >= 64) ? w2 : ((t3 >= 32) ? w1 : w0);
      if ((wm2 >> (t3 & 31)) & 1u) ko[(unsigned)(key[p] & 0xFFFFFFFFull)] = 1.0f;
    }
  }
}

extern "C" void kernel_launch(void* const* d_in, const int* in_sizes, int n_in,
                              void* d_out, int out_size, void* d_ws, size_t ws_size,
                              hipStream_t stream) {
  const float* img = (const float*)d_in[0];
  const float* w1 = (const float*)d_in[1];
  const float* b1 = (const float*)d_in[2];
  const float* w2 = (const float*)d_in[3];
  const float* b2 = (const float*)d_in[4];
  const float* w3 = (const float*)d_in[5];
  const float* b3 = (const float*)d_in[6];
  const float* wd1 = (const float*)d_in[7];
  const float* bd1 = (const float*)d_in[8];
  const float* wd2 = (const float*)d_in[9];
  const float* bd2 = (const float*)d_in[10];

  float* ws = (float*)d_ws;
  // region A (reused): conv1 output a1 lives here first, then post-conv2 stages
  float* a1 = ws + 0;                 // 9,324,800
  float* a3 = ws + 0;                 // 1,971,200
  float* a3t = ws + 1971200;          // 1,971,200
  float* pd1 = ws + 3942400;          // 963*2048 = 1,972,224
  float* d1t = ws + 5914624;          // 2048
  float* pd2 = ws + 5916672;          // 614,400
  float* d2 = ws + 6531072;           // 307,200
  float* boxd = ws + 6838272;         // 307,200
  int* cnt = (int*)(ws + 7145472);    // 24 ints
  float* p1 = ws + 9324800;           // 2,306,304
  float* a2 = ws + 11631104;          // 4,416,000
  float* p2 = ws + 16047104;          // 1,079,808  (total 17,126,912 floats = 68.5 MB)

  float* pred = (float*)d_out;
  float* keep = pred + 307200;

  k_conv1<<<(291400 + 255) / 256, 256, 0, stream>>>(img, w1, b1, a1);
  k_pool<<<(2306304 + 255) / 256, 256, 0, stream>>>(a1, p1, 8, 155, 235, 77, 117, 32);
  k_conv2<<<(276000 + 255) / 256, 256, 0, stream>>>(p1, w2, b2, a2);
  k_pool<<<(1079808 + 255) / 256, 256, 0, stream>>>(a2, p2, 8, 75, 115, 37, 57, 64);
  k_conv3<<<(123200 + 255) / 256, 256, 0, stream>>>(p2, w3, b3, a3);
  k_transpose_a3<<<(246400 + 255) / 256, 256, 0, stream>>>(a3, a3t);
  k_dense1<<<963, 256, 0, stream>>>(a3t, wd1, pd1);
  k_reduce1<<<8, 256, 0, stream>>>(pd1, bd1, d1t);
  dim3 g2(150, 2);
  k_dense2<<<g2, 256, 0, stream>>>(d1t, wd2, pd2);
  k_reduce2<<<1200, 256, 0, stream>>>(pd2, bd2, d2);
  k_transform<<<75, 256, 0, stream>>>(d2, pred, boxd);
  k_zero<<<450, 256, 0, stream>>>(keep, cnt);
  k_nms<<<24, 256, 0, stream>>>(boxd, cnt, keep);
}

// Round 2
// 678.466 us; speedup vs baseline: 1.5060x; 1.5060x over previous
//
#include <hip/hip_runtime.h>
#include <stdint.h>

// Pipeline:
// img (8,160,240,3) -> conv1 6x6 -> (8,155,235,32) -> pool -> (8,77,117,32)
// -> conv2 3x3 -> (8,75,115,64) -> pool -> (8,37,57,64)
// -> conv3 3x3 -> (8,35,55,128) -> flatten 246400 -> dense 256 -> dense 38400
// -> transform -> pred (8,40,60,16); NMS -> keep (8,3,4800)

static __device__ __forceinline__ float sigmoidf_(float x) {
  return 1.0f / (1.0f + expf(-x));
}

// ---------------- conv1: 6x6x3 -> 32 ----------------
// tile 16 rows x 32 cols out; input tile 21x37x3 in LDS; weights (3456 f) in LDS.
// 256 threads: wave w = cg (8 out ch), lane l: py=l>>2, px0=(l&3)*8; 8 pixels/thread.
__global__ __launch_bounds__(256) void k_conv1(const float* __restrict__ in,
    const float* __restrict__ w, const float* __restrict__ bias, float* __restrict__ out) {
  __shared__ float s_in[21 * 37 * 3];    // [y][x][c]
  __shared__ float s_w[6 * 6 * 3 * 32];  // [ky][kx][c][o]
  int tx = blockIdx.x, ty = blockIdx.y, n = blockIdx.z;
  int tid = threadIdx.x;
  int iy0 = ty * 16, ix0 = tx * 32;
  // stage weights
  for (int idx = tid; idx < 3456; idx += 256) s_w[idx] = w[idx];
  // stage input [y][x][c], coalesced global read
  for (int idx = tid; idx < 21 * 37 * 3; idx += 256) {
    int c = idx % 3;
    int rem = idx / 3;
    int x = rem % 37, y = rem / 37;
    int gy = iy0 + y, gx = ix0 + x;
    float v = 0.f;
    if (gy < 160 && gx < 240) v = in[((size_t)(n * 160 + gy) * 240 + gx) * 3 + c];
    s_in[idx] = v;
  }
  __syncthreads();

  int cg = tid >> 6;          // 0..3 -> out ch cg*8
  int l = tid & 63;
  int py = l >> 2;
  int px0 = (l & 3) * 8;

  float acc[8][8];
  float bj[8];
#pragma unroll
  for (int j = 0; j < 8; j++) bj[j] = bias[cg * 8 + j];
#pragma unroll
  for (int k = 0; k < 8; k++)
#pragma unroll
    for (int j = 0; j < 8; j++) acc[k][j] = bj[j];

#pragma unroll 1
  for (int ky = 0; ky < 6; ky++) {
#pragma unroll 1
    for (int kx = 0; kx < 6; kx++) {
#pragma unroll 1
      for (int c = 0; c < 3; c++) {
        const float* ib = s_in + ((py + ky) * 37 + px0 + kx) * 3 + c;
        float iv[8];
#pragma unroll
        for (int k = 0; k < 8; k++) iv[k] = ib[k * 3];
        const float* wb = s_w + ((ky * 6 + kx) * 3 + c) * 32 + cg * 8;
        float wv[8];
#pragma unroll
        for (int j = 0; j < 8; j++) wv[j] = wb[j];
#pragma unroll
        for (int k = 0; k < 8; k++)
#pragma unroll
          for (int j = 0; j < 8; j++) acc[k][j] = fmaf(iv[k], wv[j], acc[k][j]);
      }
    }
  }
  int oy = iy0 + py;
  if (oy < 155) {
#pragma unroll
    for (int k = 0; k < 8; k++) {
      int ox = ix0 + px0 + k;
      if (ox < 235) {
        float* op = out + ((size_t)(n * 155 + oy) * 235 + ox) * 32 + cg * 8;
        float4 v0, v1;
        v0.x = fmaxf(acc[k][0], 0.f); v0.y = fmaxf(acc[k][1], 0.f);
        v0.z = fmaxf(acc[k][2], 0.f); v0.w = fmaxf(acc[k][3], 0.f);
        v1.x = fmaxf(acc[k][4], 0.f); v1.y = fmaxf(acc[k][5], 0.f);
        v1.z = fmaxf(acc[k][6], 0.f); v1.w = fmaxf(acc[k][7], 0.f);
        ((float4*)op)[0] = v0;
        ((float4*)op)[1] = v1;
      }
    }
  }
}

// ---------------- 2x2 max pool, VALID ----------------
__global__ __launch_bounds__(256) void k_pool(const float* __restrict__ in, float* __restrict__ out,
    int N, int IH, int IW, int OH, int OW, int C) {
  int t = blockIdx.x * 256 + threadIdx.x;
  int total = N * OH * OW * C;
  if (t >= total) return;
  int c = t % C;
  int x = (t / C) % OW;
  int y = (t / (C * OW)) % OH;
  int n = t / (C * OW * OH);
  const float* p = in + ((size_t)(n * IH + y * 2) * IW + x * 2) * C + c;
  float a = fmaxf(p[0], p[C]);
  float b = fmaxf(p[(size_t)IW * C], p[(size_t)IW * C + C]);
  out[t] = fmaxf(a, b);
}

// ---------------- conv2: 3x3x32 -> 64 ----------------
// tile 8 rows x 16 cols out; input 10x18x32 in LDS [c][y][x]; weights from global (L1).
// 128 threads: cg = tid>>4 (8 groups x 8ch), pg = tid&15: py=pg>>1, px0=(pg&1)*8.
__global__ __launch_bounds__(128) void k_conv2(const float* __restrict__ in,
    const float* __restrict__ w, const float* __restrict__ bias, float* __restrict__ out) {
  __shared__ float s_in[32 * 10 * 18];  // [c][y][x]
  int tx = blockIdx.x, ty = blockIdx.y, n = blockIdx.z;
  int tid = threadIdx.x;
  int iy0 = ty * 8, ix0 = tx * 16;
  for (int idx = tid; idx < 10 * 18 * 32; idx += 128) {
    int c = idx & 31;
    int rem = idx >> 5;
    int x = rem % 18, y = rem / 18;
    int gy = iy0 + y, gx = ix0 + x;
    float v = 0.f;
    if (gy < 77 && gx < 117) v = in[((size_t)(n * 77 + gy) * 117 + gx) * 32 + c];
    s_in[c * 180 + y * 18 + x] = v;
  }
  __syncthreads();

  int cg = tid >> 4;
  int pg = tid & 15;
  int py = pg >> 1;
  int px0 = (pg & 1) * 8;

  float acc[8][8];
  float bj[8];
#pragma unroll
  for (int j = 0; j < 8; j++) bj[j] = bias[cg * 8 + j];
#pragma unroll
  for (int k = 0; k < 8; k++)
#pragma unroll
    for (int j = 0; j < 8; j++) acc[k][j] = bj[j];

#pragma unroll 1
  for (int ky = 0; ky < 3; ky++) {
#pragma unroll 1
    for (int kx = 0; kx < 3; kx++) {
      const float* wbase = w + (size_t)((ky * 3 + kx) * 32) * 64 + cg * 8;
      const float* ibase = s_in + (py + ky) * 18 + px0 + kx;
#pragma unroll 4
      for (int c = 0; c < 32; c++) {
        float4 wa = *(const float4*)(wbase + (size_t)c * 64);
        float4 wb = *(const float4*)(wbase + (size_t)c * 64 + 4);
        const float* ib = ibase + c * 180;
        float iv[8];
#pragma unroll
        for (int k = 0; k < 8; k++) iv[k] = ib[k];
#pragma unroll
        for (int k = 0; k < 8; k++) {
          acc[k][0] = fmaf(iv[k], wa.x, acc[k][0]);
          acc[k][1] = fmaf(iv[k], wa.y, acc[k][1]);
          acc[k][2] = fmaf(iv[k], wa.z, acc[k][2]);
          acc[k][3] = fmaf(iv[k], wa.w, acc[k][3]);
          acc[k][4] = fmaf(iv[k], wb.x, acc[k][4]);
          acc[k][5] = fmaf(iv[k], wb.y, acc[k][5]);
          acc[k][6] = fmaf(iv[k], wb.z, acc[k][6]);
          acc[k][7] = fmaf(iv[k], wb.w, acc[k][7]);
        }
      }
    }
  }
  int oy = iy0 + py;
  if (oy < 75) {
#pragma unroll
    for (int k = 0; k < 8; k++) {
      int ox = ix0 + px0 + k;
      if (ox < 115) {
        float* op = out + ((size_t)(n * 75 + oy) * 115 + ox) * 64 + cg * 8;
        float4 v0, v1;
        v0.x = fmaxf(acc[k][0], 0.f); v0.y = fmaxf(acc[k][1], 0.f);
        v0.z = fmaxf(acc[k][2], 0.f); v0.w = fmaxf(acc[k][3], 0.f);
        v1.x = fmaxf(acc[k][4], 0.f); v1.y = fmaxf(acc[k][5], 0.f);
        v1.z = fmaxf(acc[k][6], 0.f); v1.w = fmaxf(acc[k][7], 0.f);
        ((float4*)op)[0] = v0;
        ((float4*)op)[1] = v1;
      }
    }
  }
}

// ---------------- conv3: 3x3x64 -> 128 ----------------
// tile 8 rows x 16 cols out; input 10x18x64 in LDS [c][y][x] (46KB).
// 256 threads: cg = tid>>4 (16 groups x 8ch), pg = tid&15: py=pg>>1, px0=(pg&1)*8.
__global__ __launch_bounds__(256) void k_conv3(const float* __restrict__ in,
    const float* __restrict__ w, const float* __restrict__ bias, float* __restrict__ out) {
  __shared__ float s_in[64 * 10 * 18];  // [c][y][x]
  int tx = blockIdx.x, ty = blockIdx.y, n = blockIdx.z;
  int tid = threadIdx.x;
  int iy0 = ty * 8, ix0 = tx * 16;
  for (int idx = tid; idx < 10 * 18 * 64; idx += 256) {
    int c = idx & 63;
    int rem = idx >> 6;
    int x = rem % 18, y = rem / 18;
    int gy = iy0 + y, gx = ix0 + x;
    float v = 0.f;
    if (gy < 37 && gx < 57) v = in[((size_t)(n * 37 + gy) * 57 + gx) * 64 + c];
    s_in[c * 180 + y * 18 + x] = v;
  }
  __syncthreads();

  int cg = tid >> 4;
  int pg = tid & 15;
  int py = pg >> 1;
  int px0 = (pg & 1) * 8;

  float acc[8][8];
  float bj[8];
#pragma unroll
  for (int j = 0; j < 8; j++) bj[j] = bias[cg * 8 + j];
#pragma unroll
  for (int k = 0; k < 8; k++)
#pragma unroll
    for (int j = 0; j < 8; j++) acc[k][j] = bj[j];

#pragma unroll 1
  for (int ky = 0; ky < 3; ky++) {
#pragma unroll 1
    for (int kx = 0; kx < 3; kx++) {
      const float* wbase = w + (size_t)((ky * 3 + kx) * 64) * 128 + cg * 8;
      const float* ibase = s_in + (py + ky) * 18 + px0 + kx;
#pragma unroll 4
      for (int c = 0; c < 64; c++) {
        float4 wa = *(const float4*)(wbase + (size_t)c * 128);
        float4 wb = *(const float4*)(wbase + (size_t)c * 128 + 4);
        const float* ib = ibase + c * 180;
        float iv[8];
#pragma unroll
        for (int k = 0; k < 8; k++) iv[k] = ib[k];
#pragma unroll
        for (int k = 0; k < 8; k++) {
          acc[k][0] = fmaf(iv[k], wa.x, acc[k][0]);
          acc[k][1] = fmaf(iv[k], wa.y, acc[k][1]);
          acc[k][2] = fmaf(iv[k], wa.z, acc[k][2]);
          acc[k][3] = fmaf(iv[k], wa.w, acc[k][3]);
          acc[k][4] = fmaf(iv[k], wb.x, acc[k][4]);
          acc[k][5] = fmaf(iv[k], wb.y, acc[k][5]);
          acc[k][6] = fmaf(iv[k], wb.z, acc[k][6]);
          acc[k][7] = fmaf(iv[k], wb.w, acc[k][7]);
        }
      }
    }
  }
  int oy = iy0 + py;
  if (oy < 35) {
#pragma unroll
    for (int k = 0; k < 8; k++) {
      int ox = ix0 + px0 + k;
      if (ox < 55) {
        float* op = out + ((size_t)(n * 35 + oy) * 55 + ox) * 128 + cg * 8;
        float4 v0, v1;
        v0.x = fmaxf(acc[k][0], 0.f); v0.y = fmaxf(acc[k][1], 0.f);
        v0.z = fmaxf(acc[k][2], 0.f); v0.w = fmaxf(acc[k][3], 0.f);
        v1.x = fmaxf(acc[k][4], 0.f); v1.y = fmaxf(acc[k][5], 0.f);
        v1.z = fmaxf(acc[k][6], 0.f); v1.w = fmaxf(acc[k][7], 0.f);
        ((float4*)op)[0] = v0;
        ((float4*)op)[1] = v1;
      }
    }
  }
}

// ---------------- transpose a3 (8,246400) -> a3t (246400,8) ----------------
__global__ __launch_bounds__(256) void k_transpose_a3(const float* __restrict__ a3,
                                                      float* __restrict__ a3t) {
  int k = blockIdx.x * 256 + threadIdx.x;
  if (k >= 246400) return;
#pragma unroll
  for (int n = 0; n < 8; n++) a3t[(size_t)k * 8 + n] = a3[(size_t)n * 246400 + k];
}

// ---------------- dense1: (8,246400) @ (246400,256), split-K partials ----------------
// block c of 963: K rows c*256..; threads: c4 = t&63 (4 cols), ks = t>>6 (64-row sub).
__global__ __launch_bounds__(256) void k_dense1(const float* __restrict__ a3t,
    const float* __restrict__ wd1, float* __restrict__ part) {
  __shared__ float red[4][64][32];
  int c = blockIdx.x;
  int tid = threadIdx.x;
  int c4 = tid & 63;
  int ks = tid >> 6;
  int k0 = c * 256;
  int kn = 246400 - k0;
  if (kn > 256) kn = 256;
  float acc[8][4];
#pragma unroll
  for (int n = 0; n < 8; n++)
#pragma unroll
    for (int j = 0; j < 4; j++) acc[n][j] = 0.f;
  int kbeg = ks * 64;
  int kend = kbeg + 64;
  if (kend > kn) kend = kn;
#pragma unroll 1
  for (int kk = kbeg; kk < kend; kk++) {
    size_t row = (size_t)(k0 + kk);
    float4 wv = *(const float4*)(wd1 + row * 256 + c4 * 4);
    float4 xa = *(const float4*)(a3t + row * 8);
    float4 xb = *(const float4*)(a3t + row * 8 + 4);
    float xs[8] = {xa.x, xa.y, xa.z, xa.w, xb.x, xb.y, xb.z, xb.w};
#pragma unroll
    for (int n = 0; n < 8; n++) {
      acc[n][0] = fmaf(xs[n], wv.x, acc[n][0]);
      acc[n][1] = fmaf(xs[n], wv.y, acc[n][1]);
      acc[n][2] = fmaf(xs[n], wv.z, acc[n][2]);
      acc[n][3] = fmaf(xs[n], wv.w, acc[n][3]);
    }
  }
#pragma unroll
  for (int n = 0; n < 8; n++)
#pragma unroll
    for (int j = 0; j < 4; j++) red[ks][c4][n * 4 + j] = acc[n][j];
  __syncthreads();
  for (int o = tid; o < 2048; o += 256) {
    int col = o & 255, n = o >> 8;
    int cc = col >> 2, j = col & 3;
    float s = red[0][cc][n * 4 + j] + red[1][cc][n * 4 + j] +
              red[2][cc][n * 4 + j] + red[3][cc][n * 4 + j];
    part[(size_t)c * 2048 + n * 256 + col] = s;
  }
}

__global__ __launch_bounds__(256) void k_reduce1(const float* __restrict__ part,
    const float* __restrict__ bd1, float* __restrict__ d1t) {
  int t = blockIdx.x * 256 + threadIdx.x;  // 0..2047
  if (t >= 2048) return;
  float s = 0.f;
  for (int c = 0; c < 963; c++) s += part[(size_t)c * 2048 + t];
  int n = t >> 8, j = t & 255;
  float v = s + bd1[j];
  d1t[j * 8 + n] = fmaxf(v, 0.f);   // ReLU; store transposed (256,8)
}

// ---------------- dense2: (8,256) @ (256,38400), split-K ----------------
// grid (150 colblocks, 2 K-halves); threads: c4 = t&63 (4 cols), ks2 = t>>6 (32-row sub).
__global__ __launch_bounds__(256) void k_dense2(const float* __restrict__ d1t,
    const float* __restrict__ wd2, float* __restrict__ part) {
  __shared__ float red[4][64][32];
  int jb = blockIdx.x;
  int gks = blockIdx.y;
  int tid = threadIdx.x;
  int c4 = tid & 63;
  int ks2 = tid >> 6;
  int j0 = jb * 256 + c4 * 4;
  int kbeg = gks * 128 + ks2 * 32;
  float acc[8][4];
#pragma unroll
  for (int n = 0; n < 8; n++)
#pragma unroll
    for (int j = 0; j < 4; j++) acc[n][j] = 0.f;
#pragma unroll 1
  for (int kk = 0; kk < 32; kk++) {
    int row = kbeg + kk;
    float4 wv = *(const float4*)(wd2 + (size_t)row * 38400 + j0);
    float4 xa = *(const float4*)(d1t + row * 8);
    float4 xb = *(const float4*)(d1t + row * 8 + 4);
    float xs[8] = {xa.x, xa.y, xa.z, xa.w, xb.x, xb.y, xb.z, xb.w};
#pragma unroll
    for (int n = 0; n < 8; n++) {
      acc[n][0] = fmaf(xs[n], wv.x, acc[n][0]);
      acc[n][1] = fmaf(xs[n], wv.y, acc[n][1]);
      acc[n][2] = fmaf(xs[n], wv.z, acc[n][2]);
      acc[n][3] = fmaf(xs[n], wv.w, acc[n][3]);
    }
  }
#pragma unroll
  for (int n = 0; n < 8; n++)
#pragma unroll
    for (int j = 0; j < 4; j++) red[ks2][c4][n * 4 + j] = acc[n][j];
  __syncthreads();
  for (int o = tid; o < 2048; o += 256) {
    int col = o & 255, n = o >> 8;
    int cc = col >> 2, j = col & 3;
    float s = red[0][cc][n * 4 + j] + red[1][cc][n * 4 + j] +
              red[2][cc][n * 4 + j] + red[3][cc][n * 4 + j];
    part[((size_t)gks * 8 + n) * 38400 + jb * 256 + col] = s;
  }
}

__global__ __launch_bounds__(256) void k_reduce2(const float* __restrict__ part,
    const float* __restrict__ bd2, float* __restrict__ d2) {
  int t = blockIdx.x * 256 + threadIdx.x;
  if (t >= 8 * 38400) return;
  int n = t / 38400, j = t - n * 38400;
  d2[t] = part[(size_t)n * 38400 + j] + part[(size_t)(8 + n) * 38400 + j] + bd2[j];
}

// ---------------- predict_transform + per-box NMS precompute ----------------
__global__ __launch_bounds__(256) void k_transform(const float* __restrict__ d2,
    float* __restrict__ pred, float* __restrict__ boxd) {
  int t = blockIdx.x * 256 + threadIdx.x;  // 8*2400
  if (t >= 19200) return;
  int cell = t % 2400;
  int n = t / 2400;
  float gx = (float)(cell % 60), gy = (float)(cell / 60);
  const float* p = d2 + (size_t)t * 16;
  float o[16];
  o[0] = (sigmoidf_(p[0]) + gx) * 4.0f;
  o[1] = (sigmoidf_(p[1]) + gy) * 4.0f;
  o[2] = expf(p[2]) * 60.0f * 4.0f;
  o[3] = expf(p[3]) * 30.0f * 4.0f;
  o[4] = sigmoidf_(p[4]);
  o[5] = sigmoidf_(p[5]);
  o[6] = sigmoidf_(p[6]);
  o[7] = sigmoidf_(p[7]);
  o[8] = (p[8] + gx) * 4.0f;
  o[9] = (p[9] + gy) * 4.0f;
  o[10] = expf(p[10]) * 20.0f * 4.0f;
  o[11] = expf(p[11]) * 40.0f * 4.0f;
  o[12] = p[12];
  o[13] = sigmoidf_(p[13]);
  o[14] = sigmoidf_(p[14]);
  o[15] = sigmoidf_(p[15]);
  float* op = pred + (size_t)t * 16;
#pragma unroll
  for (int q = 0; q < 16; q++) op[q] = o[q];
#pragma unroll
  for (int h = 0; h < 2; h++) {
    int b = n * 4800 + h * 2400 + cell;
    float X = o[h * 8 + 0], Y = o[h * 8 + 1], W = o[h * 8 + 2], H = o[h * 8 + 3];
    float conf = o[h * 8 + 4];
    float c0 = o[h * 8 + 5], c1 = o[h * 8 + 6], c2 = o[h * 8 + 7];
    int cls = 0; float best = c0;
    if (c1 > best) { best = c1; cls = 1; }
    if (c2 > best) { best = c2; cls = 2; }
    float x1 = X - W / 2.0f, y1 = Y - H / 2.0f;
    float x2 = X + W / 2.0f, y2 = Y + H / 2.0f;
    float area = (x2 - x1 + 1.0f) * (y2 - y1 + 1.0f);
    float* bp2 = boxd + (size_t)b * 8;
    bp2[0] = x1; bp2[1] = y1; bp2[2] = x2; bp2[3] = y2;
    bp2[4] = area; bp2[5] = conf;
    ((int*)bp2)[6] = cls; bp2[7] = 0.f;
  }
}

__global__ __launch_bounds__(256) void k_zero(float* __restrict__ keep_out, int* __restrict__ cnt) {
  int t = blockIdx.x * 256 + threadIdx.x;
  if (t < 115200) keep_out[t] = 0.f;
  if (t < 24) cnt[t] = 0;
}

// ---------------- NMS: one block per (image, class) ----------------
__global__ __launch_bounds__(256) void k_nms(const float* __restrict__ boxd,
    int* __restrict__ cnt, float* __restrict__ keep_out) {
  __shared__ unsigned long long key[8192];
  int bid = blockIdx.x;  // 0..23
  int n = bid / 3, c = bid - n * 3;
  int tid = threadIdx.x;
  const float* bd = boxd + (size_t)n * 4800 * 8;
  int* myc = cnt + bid;

  for (int p = tid; p < 4800; p += 256) {
    const float* bp = bd + (size_t)p * 8;
    float conf = bp[5];
    int cls = ((const int*)bp)[6];
    if (conf > 0.5f && cls == c) {
      unsigned slot = (unsigned)atomicAdd(myc, 1);
      unsigned u = __float_as_uint(conf);
      unsigned asc = (u & 0x80000000u) ? ~u : (u | 0x80000000u);
      key[slot] = (((unsigned long long)(~asc)) << 32) | (unsigned)p;
    }
  }
  __syncthreads();
  int V = atomicAdd(myc, 0);
  if (V == 0) return;
  int Vp2 = 1;
  while (Vp2 < V) Vp2 <<= 1;
  for (int s = V + tid; s < Vp2; s += 256) key[s] = ~0ull;

  for (int k = 2; k <= Vp2; k <<= 1) {
    for (int j = k >> 1; j > 0; j >>= 1) {
      __syncthreads();
      int jm = j - 1;
      for (int t2 = tid; t2 < (Vp2 >> 1); t2 += 256) {
        int i = ((t2 & ~jm) << 1) | (t2 & jm);
        int q = i | j;
        bool up = ((i & k) == 0);
        unsigned long long a = key[i], b2 = key[q];
        if ((a > b2) == up) { key[i] = b2; key[q] = a; }
      }
    }
  }
  __syncthreads();
  if (tid >= 64) return;

  int lane = tid;
  int tmax = (V + 63) >> 6;
  unsigned w0 = 0, w1 = 0, w2 = 0;
  for (int t3 = 0; t3 < tmax; ++t3) {
    int p = lane + (t3 << 6);
    if (p < V) {
      if (t3 < 32) w0 |= 1u << t3;
      else if (t3 < 64) w1 |= 1u << (t3 - 32);
      else w2 |= 1u << (t3 - 64);
    }
  }
  for (int i = 0; i < V; i++) {
    int ti = i >> 6, li = i & 63;
    unsigned wm = (ti >= 64) ? w2 : ((ti >= 32) ? w1 : w0);
    int bit = (int)((wm >> (ti & 31)) & 1u);
    int ki = __shfl(bit, li, 64);
    if (ki == 0) continue;
    const float* bi = bd + (size_t)((unsigned)(key[i] & 0xFFFFFFFFull)) * 8;
    float ax1 = bi[0], ay1 = bi[1], ax2 = bi[2], ay2 = bi[3], aa = bi[4];
    for (int t3 = 0; t3 < tmax; ++t3) {
      int p = lane + (t3 << 6);
      unsigned wm2 = (t3 >= 64) ? w2 : ((t3 >= 32) ? w1 : w0);
      unsigned mybit = (wm2 >> (t3 & 31)) & 1u;
      if (p > i && p < V && mybit) {
        const float* bj = bd + (size_t)((unsigned)(key[p] & 0xFFFFFFFFull)) * 8;
        float iw = fminf(ax2, bj[2]) - fmaxf(ax1, bj[0]) + 1.0f;
        float ih = fminf(ay2, bj[3]) - fmaxf(ay1, bj[1]) + 1.0f;
        iw = fmaxf(iw, 0.f);
        ih = fmaxf(ih, 0.f);
        float inter = iw * ih;
        float iou = inter / (aa + bj[4] - inter);
        if (iou >= 0.4f) {
          if (t3 < 32) w0 &= ~(1u << t3);
          else if (t3 < 64) w1 &= ~(1u << (t3 - 32));
          else w2 &= ~(1u << (t3 - 64));
        }
      }
    }
  }
  float* ko = keep_out + (size_t)(n * 3 + c) * 4800;
  for (int t3 = 0; t3 < tmax; ++t3) {
    int p = lane + (t3 << 6);
    if (p < V) {
      unsigned wm2 = (t3 >= 64) ? w2 : ((t3 >= 32) ? w1 : w0);
      if ((wm2 >> (t3 & 31)) & 1u) ko[(unsigned)(key[p] & 0xFFFFFFFFull)] = 1.0f;
    }
  }
}

extern "C" void kernel_launch(void* const* d_in, const int* in_sizes, int n_in,
                              void* d_out, int out_size, void* d_ws, size_t ws_size,
                              hipStream_t stream) {
  const float* img = (const float*)d_in[0];
  const float* w1 = (const float*)d_in[1];
  const float* b1 = (const float*)d_in[2];
  const float* w2 = (const float*)d_in[3];
  const float* b2 = (const float*)d_in[4];
  const float* w3 = (const float*)d_in[5];
  const float* b3 = (const float*)d_in[6];
  const float* wd1 = (const float*)d_in[7];
  const float* bd1 = (const float*)d_in[8];
  const float* wd2 = (const float*)d_in[9];
  const float* bd2 = (const float*)d_in[10];

  float* ws = (float*)d_ws;
  float* a1 = ws + 0;                 // 9,324,800
  float* a3 = ws + 0;                 // 1,971,200 (reuses a1 region after conv3 input consumed)
  float* a3t = ws + 1971200;          // 1,971,200
  float* pd1 = ws + 3942400;          // 963*2048 = 1,972,224
  float* d1t = ws + 5914624;          // 2048
  float* pd2 = ws + 5916672;          // 614,400
  float* d2 = ws + 6531072;           // 307,200
  float* boxd = ws + 6838272;         // 307,200
  int* cnt = (int*)(ws + 7145472);    // 24 ints
  float* p1 = ws + 9324800;           // 2,306,304
  float* a2 = ws + 11631104;          // 4,416,000
  float* p2 = ws + 16047104;          // 1,079,808

  float* pred = (float*)d_out;
  float* keep = pred + 307200;

  k_conv1<<<dim3(8, 10, 8), 256, 0, stream>>>(img, w1, b1, a1);
  k_pool<<<(2306304 + 255) / 256, 256, 0, stream>>>(a1, p1, 8, 155, 235, 77, 117, 32);
  k_conv2<<<dim3(8, 10, 8), 128, 0, stream>>>(p1, w2, b2, a2);
  k_pool<<<(1079808 + 255) / 256, 256, 0, stream>>>(a2, p2, 8, 75, 115, 37, 57, 64);
  k_conv3<<<dim3(4, 5, 8), 256, 0, stream>>>(p2, w3, b3, a3);
  k_transpose_a3<<<(246400 + 255) / 256, 256, 0, stream>>>(a3, a3t);
  k_dense1<<<963, 256, 0, stream>>>(a3t, wd1, pd1);
  k_reduce1<<<8, 256, 0, stream>>>(pd1, bd1, d1t);
  dim3 g2(150, 2);
  k_dense2<<<g2, 256, 0, stream>>>(d1t, wd2, pd2);
  k_reduce2<<<1200, 256, 0, stream>>>(pd2, bd2, d2);
  k_transform<<<75, 256, 0, stream>>>(d2, pred, boxd);
  k_zero<<<450, 256, 0, stream>>>(keep, cnt);
  k_nms<<<24, 256, 0, stream>>>(boxd, cnt, keep);
}

// Round 4
// 555.741 us; speedup vs baseline: 1.8385x; 1.2208x over previous
//
#include <hip/hip_runtime.h>
#include <stdint.h>

// Pipeline:
// img (8,160,240,3) -> conv1 6x6 -> (8,155,235,32) -> pool -> (8,77,117,32)
// -> conv2 3x3 -> (8,75,115,64) -> pool -> (8,37,57,64)
// -> conv3 3x3 -> (8,35,55,128) -> flatten 246400 -> dense 256 -> dense 38400
// -> transform -> pred (8,40,60,16); NMS -> keep (8,3,4800)

static __device__ __forceinline__ float sigmoidf_(float x) {
  return 1.0f / (1.0f + expf(-x));
}

// ---------------- conv1: 6x6x3 -> 32 ----------------
__global__ __launch_bounds__(256) void k_conv1(const float* __restrict__ in,
    const float* __restrict__ w, const float* __restrict__ bias, float* __restrict__ out) {
  __shared__ float s_in[21 * 37 * 3];    // [y][x][c]
  __shared__ float s_w[6 * 6 * 3 * 32];  // [ky][kx][c][o]
  int tx = blockIdx.x, ty = blockIdx.y, n = blockIdx.z;
  int tid = threadIdx.x;
  int iy0 = ty * 16, ix0 = tx * 32;
  for (int idx = tid; idx < 3456; idx += 256) s_w[idx] = w[idx];
  for (int idx = tid; idx < 21 * 37 * 3; idx += 256) {
    int c = idx % 3;
    int rem = idx / 3;
    int x = rem % 37, y = rem / 37;
    int gy = iy0 + y, gx = ix0 + x;
    float v = 0.f;
    if (gy < 160 && gx < 240) v = in[((size_t)(n * 160 + gy) * 240 + gx) * 3 + c];
    s_in[idx] = v;
  }
  __syncthreads();

  int cg = tid >> 6;
  int l = tid & 63;
  int py = l >> 2;
  int px0 = (l & 3) * 8;

  float acc[8][8];
  float bj[8];
#pragma unroll
  for (int j = 0; j < 8; j++) bj[j] = bias[cg * 8 + j];
#pragma unroll
  for (int k = 0; k < 8; k++)
#pragma unroll
    for (int j = 0; j < 8; j++) acc[k][j] = bj[j];

#pragma unroll 1
  for (int ky = 0; ky < 6; ky++) {
#pragma unroll 1
    for (int kx = 0; kx < 6; kx++) {
#pragma unroll 1
      for (int c = 0; c < 3; c++) {
        const float* ib = s_in + ((py + ky) * 37 + px0 + kx) * 3 + c;
        float iv[8];
#pragma unroll
        for (int k = 0; k < 8; k++) iv[k] = ib[k * 3];
        const float* wb = s_w + ((ky * 6 + kx) * 3 + c) * 32 + cg * 8;
        float wv[8];
#pragma unroll
        for (int j = 0; j < 8; j++) wv[j] = wb[j];
#pragma unroll
        for (int k = 0; k < 8; k++)
#pragma unroll
          for (int j = 0; j < 8; j++) acc[k][j] = fmaf(iv[k], wv[j], acc[k][j]);
      }
    }
  }
  int oy = iy0 + py;
  if (oy < 155) {
#pragma unroll
    for (int k = 0; k < 8; k++) {
      int ox = ix0 + px0 + k;
      if (ox < 235) {
        float* op = out + ((size_t)(n * 155 + oy) * 235 + ox) * 32 + cg * 8;
        float4 v0, v1;
        v0.x = fmaxf(acc[k][0], 0.f); v0.y = fmaxf(acc[k][1], 0.f);
        v0.z = fmaxf(acc[k][2], 0.f); v0.w = fmaxf(acc[k][3], 0.f);
        v1.x = fmaxf(acc[k][4], 0.f); v1.y = fmaxf(acc[k][5], 0.f);
        v1.z = fmaxf(acc[k][6], 0.f); v1.w = fmaxf(acc[k][7], 0.f);
        ((float4*)op)[0] = v0;
        ((float4*)op)[1] = v1;
      }
    }
  }
}

// ---------------- 2x2 max pool, VALID ----------------
__global__ __launch_bounds__(256) void k_pool(const float* __restrict__ in, float* __restrict__ out,
    int N, int IH, int IW, int OH, int OW, int C) {
  int t = blockIdx.x * 256 + threadIdx.x;
  int total = N * OH * OW * C;
  if (t >= total) return;
  int c = t % C;
  int x = (t / C) % OW;
  int y = (t / (C * OW)) % OH;
  int n = t / (C * OW * OH);
  const float* p = in + ((size_t)(n * IH + y * 2) * IW + x * 2) * C + c;
  float a = fmaxf(p[0], p[C]);
  float b = fmaxf(p[(size_t)IW * C], p[(size_t)IW * C + C]);
  out[t] = fmaxf(a, b);
}

// ---------------- conv2: 3x3x32 -> 64 ----------------
__global__ __launch_bounds__(128) void k_conv2(const float* __restrict__ in,
    const float* __restrict__ w, const float* __restrict__ bias, float* __restrict__ out) {
  __shared__ float s_in[32 * 10 * 18];  // [c][y][x]
  int tx = blockIdx.x, ty = blockIdx.y, n = blockIdx.z;
  int tid = threadIdx.x;
  int iy0 = ty * 8, ix0 = tx * 16;
  for (int idx = tid; idx < 10 * 18 * 32; idx += 128) {
    int c = idx & 31;
    int rem = idx >> 5;
    int x = rem % 18, y = rem / 18;
    int gy = iy0 + y, gx = ix0 + x;
    float v = 0.f;
    if (gy < 77 && gx < 117) v = in[((size_t)(n * 77 + gy) * 117 + gx) * 32 + c];
    s_in[c * 180 + y * 18 + x] = v;
  }
  __syncthreads();

  int cg = tid >> 4;
  int pg = tid & 15;
  int py = pg >> 1;
  int px0 = (pg & 1) * 8;

  float acc[8][8];
  float bj[8];
#pragma unroll
  for (int j = 0; j < 8; j++) bj[j] = bias[cg * 8 + j];
#pragma unroll
  for (int k = 0; k < 8; k++)
#pragma unroll
    for (int j = 0; j < 8; j++) acc[k][j] = bj[j];

#pragma unroll 1
  for (int ky = 0; ky < 3; ky++) {
#pragma unroll 1
    for (int kx = 0; kx < 3; kx++) {
      const float* wbase = w + (size_t)((ky * 3 + kx) * 32) * 64 + cg * 8;
      const float* ibase = s_in + (py + ky) * 18 + px0 + kx;
#pragma unroll 4
      for (int c = 0; c < 32; c++) {
        float4 wa = *(const float4*)(wbase + (size_t)c * 64);
        float4 wb = *(const float4*)(wbase + (size_t)c * 64 + 4);
        const float* ib = ibase + c * 180;
        float iv[8];
#pragma unroll
        for (int k = 0; k < 8; k++) iv[k] = ib[k];
#pragma unroll
        for (int k = 0; k < 8; k++) {
          acc[k][0] = fmaf(iv[k], wa.x, acc[k][0]);
          acc[k][1] = fmaf(iv[k], wa.y, acc[k][1]);
          acc[k][2] = fmaf(iv[k], wa.z, acc[k][2]);
          acc[k][3] = fmaf(iv[k], wa.w, acc[k][3]);
          acc[k][4] = fmaf(iv[k], wb.x, acc[k][4]);
          acc[k][5] = fmaf(iv[k], wb.y, acc[k][5]);
          acc[k][6] = fmaf(iv[k], wb.z, acc[k][6]);
          acc[k][7] = fmaf(iv[k], wb.w, acc[k][7]);
        }
      }
    }
  }
  int oy = iy0 + py;
  if (oy < 75) {
#pragma unroll
    for (int k = 0; k < 8; k++) {
      int ox = ix0 + px0 + k;
      if (ox < 115) {
        float* op = out + ((size_t)(n * 75 + oy) * 115 + ox) * 64 + cg * 8;
        float4 v0, v1;
        v0.x = fmaxf(acc[k][0], 0.f); v0.y = fmaxf(acc[k][1], 0.f);
        v0.z = fmaxf(acc[k][2], 0.f); v0.w = fmaxf(acc[k][3], 0.f);
        v1.x = fmaxf(acc[k][4], 0.f); v1.y = fmaxf(acc[k][5], 0.f);
        v1.z = fmaxf(acc[k][6], 0.f); v1.w = fmaxf(acc[k][7], 0.f);
        ((float4*)op)[0] = v0;
        ((float4*)op)[1] = v1;
      }
    }
  }
}

// ---------------- conv3: 3x3x64 -> 128 ----------------
__global__ __launch_bounds__(256) void k_conv3(const float* __restrict__ in,
    const float* __restrict__ w, const float* __restrict__ bias, float* __restrict__ out) {
  __shared__ float s_in[64 * 10 * 18];  // [c][y][x]
  int tx = blockIdx.x, ty = blockIdx.y, n = blockIdx.z;
  int tid = threadIdx.x;
  int iy0 = ty * 8, ix0 = tx * 16;
  for (int idx = tid; idx < 10 * 18 * 64; idx += 256) {
    int c = idx & 63;
    int rem = idx >> 6;
    int x = rem % 18, y = rem / 18;
    int gy = iy0 + y, gx = ix0 + x;
    float v = 0.f;
    if (gy < 37 && gx < 57) v = in[((size_t)(n * 37 + gy) * 57 + gx) * 64 + c];
    s_in[c * 180 + y * 18 + x] = v;
  }
  __syncthreads();

  int cg = tid >> 4;
  int pg = tid & 15;
  int py = pg >> 1;
  int px0 = (pg & 1) * 8;

  float acc[8][8];
  float bj[8];
#pragma unroll
  for (int j = 0; j < 8; j++) bj[j] = bias[cg * 8 + j];
#pragma unroll
  for (int k = 0; k < 8; k++)
#pragma unroll
    for (int j = 0; j < 8; j++) acc[k][j] = bj[j];

#pragma unroll 1
  for (int ky = 0; ky < 3; ky++) {
#pragma unroll 1
    for (int kx = 0; kx < 3; kx++) {
      const float* wbase = w + (size_t)((ky * 3 + kx) * 64) * 128 + cg * 8;
      const float* ibase = s_in + (py + ky) * 18 + px0 + kx;
#pragma unroll 4
      for (int c = 0; c < 64; c++) {
        float4 wa = *(const float4*)(wbase + (size_t)c * 128);
        float4 wb = *(const float4*)(wbase + (size_t)c * 128 + 4);
        const float* ib = ibase + c * 180;
        float iv[8];
#pragma unroll
        for (int k = 0; k < 8; k++) iv[k] = ib[k];
#pragma unroll
        for (int k = 0; k < 8; k++) {
          acc[k][0] = fmaf(iv[k], wa.x, acc[k][0]);
          acc[k][1] = fmaf(iv[k], wa.y, acc[k][1]);
          acc[k][2] = fmaf(iv[k], wa.z, acc[k][2]);
          acc[k][3] = fmaf(iv[k], wa.w, acc[k][3]);
          acc[k][4] = fmaf(iv[k], wb.x, acc[k][4]);
          acc[k][5] = fmaf(iv[k], wb.y, acc[k][5]);
          acc[k][6] = fmaf(iv[k], wb.z, acc[k][6]);
          acc[k][7] = fmaf(iv[k], wb.w, acc[k][7]);
        }
      }
    }
  }
  int oy = iy0 + py;
  if (oy < 35) {
#pragma unroll
    for (int k = 0; k < 8; k++) {
      int ox = ix0 + px0 + k;
      if (ox < 55) {
        float* op = out + ((size_t)(n * 35 + oy) * 55 + ox) * 128 + cg * 8;
        float4 v0, v1;
        v0.x = fmaxf(acc[k][0], 0.f); v0.y = fmaxf(acc[k][1], 0.f);
        v0.z = fmaxf(acc[k][2], 0.f); v0.w = fmaxf(acc[k][3], 0.f);
        v1.x = fmaxf(acc[k][4], 0.f); v1.y = fmaxf(acc[k][5], 0.f);
        v1.z = fmaxf(acc[k][6], 0.f); v1.w = fmaxf(acc[k][7], 0.f);
        ((float4*)op)[0] = v0;
        ((float4*)op)[1] = v1;
      }
    }
  }
}

// ---------------- transpose a3 (8,246400) -> a3t (246400,8) ----------------
__global__ __launch_bounds__(256) void k_transpose_a3(const float* __restrict__ a3,
                                                      float* __restrict__ a3t) {
  int k = blockIdx.x * 256 + threadIdx.x;
  if (k >= 246400) return;
#pragma unroll
  for (int n = 0; n < 8; n++) a3t[(size_t)k * 8 + n] = a3[(size_t)n * 246400 + k];
}

// ---------------- dense1: (8,246400) @ (246400,256), split-K partials ----------------
__global__ __launch_bounds__(256) void k_dense1(const float* __restrict__ a3t,
    const float* __restrict__ wd1, float* __restrict__ part) {
  __shared__ float red[4][64][32];
  int c = blockIdx.x;
  int tid = threadIdx.x;
  int c4 = tid & 63;
  int ks = tid >> 6;
  int k0 = c * 256;
  int kn = 246400 - k0;
  if (kn > 256) kn = 256;
  float acc[8][4];
#pragma unroll
  for (int n = 0; n < 8; n++)
#pragma unroll
    for (int j = 0; j < 4; j++) acc[n][j] = 0.f;
  int kbeg = ks * 64;
  int kend = kbeg + 64;
  if (kend > kn) kend = kn;
#pragma unroll 1
  for (int kk = kbeg; kk < kend; kk++) {
    size_t row = (size_t)(k0 + kk);
    float4 wv = *(const float4*)(wd1 + row * 256 + c4 * 4);
    float4 xa = *(const float4*)(a3t + row * 8);
    float4 xb = *(const float4*)(a3t + row * 8 + 4);
    float xs[8] = {xa.x, xa.y, xa.z, xa.w, xb.x, xb.y, xb.z, xb.w};
#pragma unroll
    for (int n = 0; n < 8; n++) {
      acc[n][0] = fmaf(xs[n], wv.x, acc[n][0]);
      acc[n][1] = fmaf(xs[n], wv.y, acc[n][1]);
      acc[n][2] = fmaf(xs[n], wv.z, acc[n][2]);
      acc[n][3] = fmaf(xs[n], wv.w, acc[n][3]);
    }
  }
#pragma unroll
  for (int n = 0; n < 8; n++)
#pragma unroll
    for (int j = 0; j < 4; j++) red[ks][c4][n * 4 + j] = acc[n][j];
  __syncthreads();
  for (int o = tid; o < 2048; o += 256) {
    int col = o & 255, n = o >> 8;
    int cc = col >> 2, j = col & 3;
    float s = red[0][cc][n * 4 + j] + red[1][cc][n * 4 + j] +
              red[2][cc][n * 4 + j] + red[3][cc][n * 4 + j];
    part[(size_t)c * 2048 + n * 256 + col] = s;
  }
}

__global__ __launch_bounds__(256) void k_reduce1(const float* __restrict__ part,
    const float* __restrict__ bd1, float* __restrict__ d1t) {
  int t = blockIdx.x * 256 + threadIdx.x;  // 0..2047
  if (t >= 2048) return;
  float s = 0.f;
  for (int c = 0; c < 963; c++) s += part[(size_t)c * 2048 + t];
  int n = t >> 8, j = t & 255;
  float v = s + bd1[j];
  d1t[j * 8 + n] = fmaxf(v, 0.f);   // ReLU; store transposed (256,8)
}

// ---------------- dense2: (8,256) @ (256,38400), split-K ----------------
__global__ __launch_bounds__(256) void k_dense2(const float* __restrict__ d1t,
    const float* __restrict__ wd2, float* __restrict__ part) {
  __shared__ float red[4][64][32];
  int jb = blockIdx.x;
  int gks = blockIdx.y;
  int tid = threadIdx.x;
  int c4 = tid & 63;
  int ks2 = tid >> 6;
  int j0 = jb * 256 + c4 * 4;
  int kbeg = gks * 128 + ks2 * 32;
  float acc[8][4];
#pragma unroll
  for (int n = 0; n < 8; n++)
#pragma unroll
    for (int j = 0; j < 4; j++) acc[n][j] = 0.f;
#pragma unroll 1
  for (int kk = 0; kk < 32; kk++) {
    int row = kbeg + kk;
    float4 wv = *(const float4*)(wd2 + (size_t)row * 38400 + j0);
    float4 xa = *(const float4*)(d1t + row * 8);
    float4 xb = *(const float4*)(d1t + row * 8 + 4);
    float xs[8] = {xa.x, xa.y, xa.z, xa.w, xb.x, xb.y, xb.z, xb.w};
#pragma unroll
    for (int n = 0; n < 8; n++) {
      acc[n][0] = fmaf(xs[n], wv.x, acc[n][0]);
      acc[n][1] = fmaf(xs[n], wv.y, acc[n][1]);
      acc[n][2] = fmaf(xs[n], wv.z, acc[n][2]);
      acc[n][3] = fmaf(xs[n], wv.w, acc[n][3]);
    }
  }
#pragma unroll
  for (int n = 0; n < 8; n++)
#pragma unroll
    for (int j = 0; j < 4; j++) red[ks2][c4][n * 4 + j] = acc[n][j];
  __syncthreads();
  for (int o = tid; o < 2048; o += 256) {
    int col = o & 255, n = o >> 8;
    int cc = col >> 2, j = col & 3;
    float s = red[0][cc][n * 4 + j] + red[1][cc][n * 4 + j] +
              red[2][cc][n * 4 + j] + red[3][cc][n * 4 + j];
    part[((size_t)gks * 8 + n) * 38400 + jb * 256 + col] = s;
  }
}

__global__ __launch_bounds__(256) void k_reduce2(const float* __restrict__ part,
    const float* __restrict__ bd2, float* __restrict__ d2) {
  int t = blockIdx.x * 256 + threadIdx.x;
  if (t >= 8 * 38400) return;
  int n = t / 38400, j = t - n * 38400;
  d2[t] = part[(size_t)n * 38400 + j] + part[(size_t)(8 + n) * 38400 + j] + bd2[j];
}

// ---------------- predict_transform + per-box NMS precompute ----------------
__global__ __launch_bounds__(256) void k_transform(const float* __restrict__ d2,
    float* __restrict__ pred, float* __restrict__ boxd) {
  int t = blockIdx.x * 256 + threadIdx.x;  // 8*2400
  if (t >= 19200) return;
  int cell = t % 2400;
  int n = t / 2400;
  float gx = (float)(cell % 60), gy = (float)(cell / 60);
  const float* p = d2 + (size_t)t * 16;
  float o[16];
  o[0] = (sigmoidf_(p[0]) + gx) * 4.0f;
  o[1] = (sigmoidf_(p[1]) + gy) * 4.0f;
  o[2] = expf(p[2]) * 60.0f * 4.0f;
  o[3] = expf(p[3]) * 30.0f * 4.0f;
  o[4] = sigmoidf_(p[4]);
  o[5] = sigmoidf_(p[5]);
  o[6] = sigmoidf_(p[6]);
  o[7] = sigmoidf_(p[7]);
  o[8] = (p[8] + gx) * 4.0f;
  o[9] = (p[9] + gy) * 4.0f;
  o[10] = expf(p[10]) * 20.0f * 4.0f;
  o[11] = expf(p[11]) * 40.0f * 4.0f;
  o[12] = p[12];
  o[13] = sigmoidf_(p[13]);
  o[14] = sigmoidf_(p[14]);
  o[15] = sigmoidf_(p[15]);
  float* op = pred + (size_t)t * 16;
#pragma unroll
  for (int q = 0; q < 16; q++) op[q] = o[q];
#pragma unroll
  for (int h = 0; h < 2; h++) {
    int b = n * 4800 + h * 2400 + cell;
    float X = o[h * 8 + 0], Y = o[h * 8 + 1], W = o[h * 8 + 2], H = o[h * 8 + 3];
    float conf = o[h * 8 + 4];
    float c0 = o[h * 8 + 5], c1 = o[h * 8 + 6], c2 = o[h * 8 + 7];
    int cls = 0; float best = c0;
    if (c1 > best) { best = c1; cls = 1; }
    if (c2 > best) { best = c2; cls = 2; }
    float x1 = X - W / 2.0f, y1 = Y - H / 2.0f;
    float x2 = X + W / 2.0f, y2 = Y + H / 2.0f;
    float area = (x2 - x1 + 1.0f) * (y2 - y1 + 1.0f);
    float* bp2 = boxd + (size_t)b * 8;
    bp2[0] = x1; bp2[1] = y1; bp2[2] = x2; bp2[3] = y2;
    bp2[4] = area; bp2[5] = conf;
    ((int*)bp2)[6] = cls; bp2[7] = 0.f;
  }
}

__global__ __launch_bounds__(256) void k_zero(float* __restrict__ keep_out) {
  int t = blockIdx.x * 256 + threadIdx.x;
  if (t < 115200) keep_out[t] = 0.f;
}

// ---------------- NMS: one block per (image, class), fully LDS-resident ----------------
// Phase 1: compact valid boxes, bitonic-sort (score desc, idx asc) in key[].
// Phase 2: stage sorted box coords into LDS.
// Phase 3: greedy scan over KEPT boxes only (find-min-avail bit), 256-thread
//          parallel IoU suppression against the LDS availability bitmask.
__global__ __launch_bounds__(256) void k_nms(const float* __restrict__ boxd,
    float* __restrict__ keep_out) {
  __shared__ unsigned long long key[8192];  // 64 KB (sort keys; low32 = orig idx)
  __shared__ float4 sbox[4800];             // 76.8 KB sorted x1,y1,x2,y2
  __shared__ unsigned avail[150];           // availability bitmask over sorted idx
  __shared__ int scnt;
  __shared__ int s_sel;
  int bid = blockIdx.x;  // 0..23
  int n = bid / 3, c = bid - n * 3;
  int tid = threadIdx.x;
  const float* bd = boxd + (size_t)n * 4800 * 8;
  if (tid == 0) scnt = 0;
  __syncthreads();

  // ---- compact ----
  for (int p = tid; p < 4800; p += 256) {
    const float* bp = bd + (size_t)p * 8;
    float conf = bp[5];
    int cls = ((const int*)bp)[6];
    if (conf > 0.5f && cls == c) {
      int slot = atomicAdd(&scnt, 1);
      unsigned u = __float_as_uint(conf);
      unsigned asc = (u & 0x80000000u) ? ~u : (u | 0x80000000u);
      key[slot] = (((unsigned long long)(~asc)) << 32) | (unsigned)p;
    }
  }
  __syncthreads();
  int V = scnt;
  if (V == 0) return;
  int Vp2 = 1;
  while (Vp2 < V) Vp2 <<= 1;
  for (int s = V + tid; s < Vp2; s += 256) key[s] = ~0ull;

  // ---- bitonic sort ascending -> score desc, idx asc (stable argsort(-score)) ----
  for (int k = 2; k <= Vp2; k <<= 1) {
    for (int j = k >> 1; j > 0; j >>= 1) {
      __syncthreads();
      int jm = j - 1;
      for (int t2 = tid; t2 < (Vp2 >> 1); t2 += 256) {
        int i = ((t2 & ~jm) << 1) | (t2 & jm);
        int q = i | j;
        bool up = ((i & k) == 0);
        unsigned long long a = key[i], b2 = key[q];
        if ((a > b2) == up) { key[i] = b2; key[q] = a; }
      }
    }
  }
  __syncthreads();

  // ---- stage sorted boxes + init availability ----
  for (int s = tid; s < V; s += 256) {
    unsigned p = (unsigned)(key[s] & 0xFFFFFFFFull);
    const float* bp = bd + (size_t)p * 8;
    float4 b4;
    b4.x = bp[0]; b4.y = bp[1]; b4.z = bp[2]; b4.w = bp[3];
    sbox[s] = b4;
  }
  for (int w = tid; w < 150; w += 256) {
    int rem = V - (w << 5);
    avail[w] = (rem >= 32) ? 0xFFFFFFFFu : (rem <= 0 ? 0u : ((1u << rem) - 1u));
  }
  __syncthreads();

  // ---- greedy: K iterations (kept boxes only) ----
  float* ko = keep_out + (size_t)bid * 4800;
  for (;;) {
    if (tid < 64) {
      int cand = 0x7FFFFFFF;
      for (int w = tid; w < 150; w += 64) {
        unsigned a = avail[w];
        if (a) {
          int c2 = (w << 5) + __ffs(a) - 1;
          if (c2 < cand) cand = c2;
        }
      }
      for (int off = 32; off > 0; off >>= 1) {
        int o = __shfl_xor(cand, off, 64);
        if (o < cand) cand = o;
      }
      if (tid == 0) s_sel = cand;
    }
    __syncthreads();
    int i = s_sel;
    if (i == 0x7FFFFFFF) break;
    float4 bi = sbox[i];
    float ai = (bi.z - bi.x + 1.0f) * (bi.w - bi.y + 1.0f);
    if (tid == 0) {
      ko[(unsigned)(key[i] & 0xFFFFFFFFull)] = 1.0f;
      avail[i >> 5] &= ~(1u << (i & 31));
    }
    __syncthreads();
    for (int j = i + 1 + tid; j < V; j += 256) {
      if (!((avail[j >> 5] >> (j & 31)) & 1u)) continue;
      float4 bj = sbox[j];
      float iw = fminf(bi.z, bj.z) - fmaxf(bi.x, bj.x) + 1.0f;
      float ih = fminf(bi.w, bj.w) - fmaxf(bi.y, bj.y) + 1.0f;
      iw = fmaxf(iw, 0.f);
      ih = fmaxf(ih, 0.f);
      float inter = iw * ih;
      float aj = (bj.z - bj.x + 1.0f) * (bj.w - bj.y + 1.0f);
      float iou = inter / (ai + aj - inter);
      if (iou >= 0.4f) atomicAnd(&avail[j >> 5], ~(1u << (j & 31)));
    }
    __syncthreads();
  }
}

extern "C" void kernel_launch(void* const* d_in, const int* in_sizes, int n_in,
                              void* d_out, int out_size, void* d_ws, size_t ws_size,
                              hipStream_t stream) {
  const float* img = (const float*)d_in[0];
  const float* w1 = (const float*)d_in[1];
  const float* b1 = (const float*)d_in[2];
  const float* w2 = (const float*)d_in[3];
  const float* b2 = (const float*)d_in[4];
  const float* w3 = (const float*)d_in[5];
  const float* b3 = (const float*)d_in[6];
  const float* wd1 = (const float*)d_in[7];
  const float* bd1 = (const float*)d_in[8];
  const float* wd2 = (const float*)d_in[9];
  const float* bd2 = (const float*)d_in[10];

  float* ws = (float*)d_ws;
  float* a1 = ws + 0;                 // 9,324,800
  float* a3 = ws + 0;                 // 1,971,200 (reuses a1 region)
  float* a3t = ws + 1971200;          // 1,971,200
  float* pd1 = ws + 3942400;          // 1,972,224
  float* d1t = ws + 5914624;          // 2048
  float* pd2 = ws + 5916672;          // 614,400
  float* d2 = ws + 6531072;           // 307,200
  float* boxd = ws + 6838272;         // 307,200
  float* p1 = ws + 9324800;           // 2,306,304
  float* a2 = ws + 11631104;          // 4,416,000
  float* p2 = ws + 16047104;          // 1,079,808

  float* pred = (float*)d_out;
  float* keep = pred + 307200;

  k_conv1<<<dim3(8, 10, 8), 256, 0, stream>>>(img, w1, b1, a1);
  k_pool<<<(2306304 + 255) / 256, 256, 0, stream>>>(a1, p1, 8, 155, 235, 77, 117, 32);
  k_conv2<<<dim3(8, 10, 8), 128, 0, stream>>>(p1, w2, b2, a2);
  k_pool<<<(1079808 + 255) / 256, 256, 0, stream>>>(a2, p2, 8, 75, 115, 37, 57, 64);
  k_conv3<<<dim3(4, 5, 8), 256, 0, stream>>>(p2, w3, b3, a3);
  k_transpose_a3<<<(246400 + 255) / 256, 256, 0, stream>>>(a3, a3t);
  k_dense1<<<963, 256, 0, stream>>>(a3t, wd1, pd1);
  k_reduce1<<<8, 256, 0, stream>>>(pd1, bd1, d1t);
  dim3 g2(150, 2);
  k_dense2<<<g2, 256, 0, stream>>>(d1t, wd2, pd2);
  k_reduce2<<<1200, 256, 0, stream>>>(pd2, bd2, d2);
  k_transform<<<75, 256, 0, stream>>>(d2, pred, boxd);
  k_zero<<<450, 256, 0, stream>>>(keep);
  k_nms<<<24, 256, 0, stream>>>(boxd, keep);
}

// Round 5
// 470.502 us; speedup vs baseline: 2.1716x; 1.1812x over previous
//
#include <hip/hip_runtime.h>
#include <stdint.h>

// Pipeline:
// img (8,160,240,3) -> conv1 6x6 (+fused 2x2 pool) -> (8,77,117,32)
// -> conv2 3x3 (+fused 2x2 pool) -> (8,37,57,64)
// -> conv3 3x3 -> (8,35,55,128) -> flatten 246400 -> dense 256 -> dense 38400
// -> transform -> pred (8,40,60,16); NMS -> keep (8,3,4800)

static __device__ __forceinline__ float sigmoidf_(float x) {
  return 1.0f / (1.0f + expf(-x));
}

// ---------------- conv1 6x6x3->32 + fused 2x2 maxpool ----------------
// conv tile 16 rows x 32 cols; 256 thr: cg=tid>>6 (8 ch), l=tid&63: py=l>>2, px0=(l&3)*8.
// pool: row pairs (py,py+1) via __shfl_down 4; col pairs within thread's 8 px.
__global__ __launch_bounds__(256) void k_conv1p(const float* __restrict__ in,
    const float* __restrict__ w, const float* __restrict__ bias, float* __restrict__ out) {
  __shared__ float s_in[21 * 37 * 3];    // [y][x][c]
  __shared__ float s_w[6 * 6 * 3 * 32];  // [ky][kx][c][o]
  int tx = blockIdx.x, ty = blockIdx.y, n = blockIdx.z;
  int tid = threadIdx.x;
  int iy0 = ty * 16, ix0 = tx * 32;
  for (int idx = tid; idx < 3456; idx += 256) s_w[idx] = w[idx];
  for (int idx = tid; idx < 21 * 37 * 3; idx += 256) {
    int c = idx % 3;
    int rem = idx / 3;
    int x = rem % 37, y = rem / 37;
    int gy = iy0 + y, gx = ix0 + x;
    float v = 0.f;
    if (gy < 160 && gx < 240) v = in[((size_t)(n * 160 + gy) * 240 + gx) * 3 + c];
    s_in[idx] = v;
  }
  __syncthreads();

  int cg = tid >> 6;
  int l = tid & 63;
  int py = l >> 2;
  int px0 = (l & 3) * 8;

  float acc[8][8];
  float bj[8];
#pragma unroll
  for (int j = 0; j < 8; j++) bj[j] = bias[cg * 8 + j];
#pragma unroll
  for (int k = 0; k < 8; k++)
#pragma unroll
    for (int j = 0; j < 8; j++) acc[k][j] = bj[j];

#pragma unroll 1
  for (int ky = 0; ky < 6; ky++) {
#pragma unroll 1
    for (int kx = 0; kx < 6; kx++) {
#pragma unroll 1
      for (int c = 0; c < 3; c++) {
        const float* ib = s_in + ((py + ky) * 37 + px0 + kx) * 3 + c;
        float iv[8];
#pragma unroll
        for (int k = 0; k < 8; k++) iv[k] = ib[k * 3];
        const float* wb = s_w + ((ky * 6 + kx) * 3 + c) * 32 + cg * 8;
        float wv[8];
#pragma unroll
        for (int j = 0; j < 8; j++) wv[j] = wb[j];
#pragma unroll
        for (int k = 0; k < 8; k++)
#pragma unroll
          for (int j = 0; j < 8; j++) acc[k][j] = fmaf(iv[k], wv[j], acc[k][j]);
      }
    }
  }
  // pool 2x2: col pairs in-thread, row pairs via shfl from lane l+4 (py+1)
  float pm[4][8];
#pragma unroll
  for (int kk = 0; kk < 4; kk++)
#pragma unroll
    for (int j = 0; j < 8; j++) pm[kk][j] = fmaxf(acc[2 * kk][j], acc[2 * kk + 1][j]);
#pragma unroll
  for (int kk = 0; kk < 4; kk++)
#pragma unroll
    for (int j = 0; j < 8; j++) {
      float o = __shfl_down(pm[kk][j], 4);
      pm[kk][j] = fmaxf(pm[kk][j], o);
    }
  if (!(py & 1)) {
    int pyp = ty * 8 + (py >> 1);
    if (pyp < 77) {
#pragma unroll
      for (int kk = 0; kk < 4; kk++) {
        int pxp = tx * 16 + (l & 3) * 4 + kk;
        if (pxp < 117) {
          float* op = out + ((size_t)(n * 77 + pyp) * 117 + pxp) * 32 + cg * 8;
          float4 v0, v1;
          v0.x = fmaxf(pm[kk][0], 0.f); v0.y = fmaxf(pm[kk][1], 0.f);
          v0.z = fmaxf(pm[kk][2], 0.f); v0.w = fmaxf(pm[kk][3], 0.f);
          v1.x = fmaxf(pm[kk][4], 0.f); v1.y = fmaxf(pm[kk][5], 0.f);
          v1.z = fmaxf(pm[kk][6], 0.f); v1.w = fmaxf(pm[kk][7], 0.f);
          ((float4*)op)[0] = v0;
          ((float4*)op)[1] = v1;
        }
      }
    }
  }
}

// ---------------- conv2 3x3x32->64 + fused 2x2 maxpool ----------------
// conv tile 8 rows x 16 cols; 128 thr: cg=tid>>4, pg=tid&15: py=pg>>1, px0=(pg&1)*8.
// pool: row pairs via __shfl_down 2; col pairs within thread.
__global__ __launch_bounds__(128) void k_conv2p(const float* __restrict__ in,
    const float* __restrict__ w, const float* __restrict__ bias, float* __restrict__ out) {
  __shared__ float s_in[32 * 10 * 18];  // [c][y][x]
  int tx = blockIdx.x, ty = blockIdx.y, n = blockIdx.z;
  int tid = threadIdx.x;
  int iy0 = ty * 8, ix0 = tx * 16;
  for (int idx = tid; idx < 10 * 18 * 32; idx += 128) {
    int c = idx & 31;
    int rem = idx >> 5;
    int x = rem % 18, y = rem / 18;
    int gy = iy0 + y, gx = ix0 + x;
    float v = 0.f;
    if (gy < 77 && gx < 117) v = in[((size_t)(n * 77 + gy) * 117 + gx) * 32 + c];
    s_in[c * 180 + y * 18 + x] = v;
  }
  __syncthreads();

  int cg = tid >> 4;
  int pg = tid & 15;
  int py = pg >> 1;
  int px0 = (pg & 1) * 8;

  float acc[8][8];
  float bj[8];
#pragma unroll
  for (int j = 0; j < 8; j++) bj[j] = bias[cg * 8 + j];
#pragma unroll
  for (int k = 0; k < 8; k++)
#pragma unroll
    for (int j = 0; j < 8; j++) acc[k][j] = bj[j];

#pragma unroll 1
  for (int ky = 0; ky < 3; ky++) {
#pragma unroll 1
    for (int kx = 0; kx < 3; kx++) {
      const float* wbase = w + (size_t)((ky * 3 + kx) * 32) * 64 + cg * 8;
      const float* ibase = s_in + (py + ky) * 18 + px0 + kx;
#pragma unroll 4
      for (int c = 0; c < 32; c++) {
        float4 wa = *(const float4*)(wbase + (size_t)c * 64);
        float4 wb = *(const float4*)(wbase + (size_t)c * 64 + 4);
        const float* ib = ibase + c * 180;
        float iv[8];
#pragma unroll
        for (int k = 0; k < 8; k++) iv[k] = ib[k];
#pragma unroll
        for (int k = 0; k < 8; k++) {
          acc[k][0] = fmaf(iv[k], wa.x, acc[k][0]);
          acc[k][1] = fmaf(iv[k], wa.y, acc[k][1]);
          acc[k][2] = fmaf(iv[k], wa.z, acc[k][2]);
          acc[k][3] = fmaf(iv[k], wa.w, acc[k][3]);
          acc[k][4] = fmaf(iv[k], wb.x, acc[k][4]);
          acc[k][5] = fmaf(iv[k], wb.y, acc[k][5]);
          acc[k][6] = fmaf(iv[k], wb.z, acc[k][6]);
          acc[k][7] = fmaf(iv[k], wb.w, acc[k][7]);
        }
      }
    }
  }
  float pm[4][8];
#pragma unroll
  for (int kk = 0; kk < 4; kk++)
#pragma unroll
    for (int j = 0; j < 8; j++) pm[kk][j] = fmaxf(acc[2 * kk][j], acc[2 * kk + 1][j]);
#pragma unroll
  for (int kk = 0; kk < 4; kk++)
#pragma unroll
    for (int j = 0; j < 8; j++) {
      float o = __shfl_down(pm[kk][j], 2);
      pm[kk][j] = fmaxf(pm[kk][j], o);
    }
  if (!(pg & 2)) {
    int pyp = ty * 4 + (py >> 1);
    if (pyp < 37) {
#pragma unroll
      for (int kk = 0; kk < 4; kk++) {
        int pxp = tx * 8 + (pg & 1) * 4 + kk;
        if (pxp < 57) {
          float* op = out + ((size_t)(n * 37 + pyp) * 57 + pxp) * 64 + cg * 8;
          float4 v0, v1;
          v0.x = fmaxf(pm[kk][0], 0.f); v0.y = fmaxf(pm[kk][1], 0.f);
          v0.z = fmaxf(pm[kk][2], 0.f); v0.w = fmaxf(pm[kk][3], 0.f);
          v1.x = fmaxf(pm[kk][4], 0.f); v1.y = fmaxf(pm[kk][5], 0.f);
          v1.z = fmaxf(pm[kk][6], 0.f); v1.w = fmaxf(pm[kk][7], 0.f);
          ((float4*)op)[0] = v0;
          ((float4*)op)[1] = v1;
        }
      }
    }
  }
}

// ---------------- conv3: 3x3x64 -> 128, channel-split x2 for occupancy ----------------
// grid (4,5,16): z = n*2 + half; 256 thr: cg=tid>>4 (16 groups x 4ch), pg=tid&15.
__global__ __launch_bounds__(256) void k_conv3(const float* __restrict__ in,
    const float* __restrict__ w, const float* __restrict__ bias, float* __restrict__ out) {
  __shared__ float s_in[64 * 10 * 18];  // [c][y][x]
  int tx = blockIdx.x, ty = blockIdx.y, z = blockIdx.z;
  int n = z >> 1, h = z & 1;
  int tid = threadIdx.x;
  int iy0 = ty * 8, ix0 = tx * 16;
  for (int idx = tid; idx < 10 * 18 * 64; idx += 256) {
    int c = idx & 63;
    int rem = idx >> 6;
    int x = rem % 18, y = rem / 18;
    int gy = iy0 + y, gx = ix0 + x;
    float v = 0.f;
    if (gy < 37 && gx < 57) v = in[((size_t)(n * 37 + gy) * 57 + gx) * 64 + c];
    s_in[c * 180 + y * 18 + x] = v;
  }
  __syncthreads();

  int cg = tid >> 4;
  int pg = tid & 15;
  int py = pg >> 1;
  int px0 = (pg & 1) * 8;
  int ob = h * 64 + cg * 4;  // out channel base

  float acc[8][4];
  float bj[4];
#pragma unroll
  for (int j = 0; j < 4; j++) bj[j] = bias[ob + j];
#pragma unroll
  for (int k = 0; k < 8; k++)
#pragma unroll
    for (int j = 0; j < 4; j++) acc[k][j] = bj[j];

#pragma unroll 1
  for (int ky = 0; ky < 3; ky++) {
#pragma unroll 1
    for (int kx = 0; kx < 3; kx++) {
      const float* wbase = w + (size_t)((ky * 3 + kx) * 64) * 128 + ob;
      const float* ibase = s_in + (py + ky) * 18 + px0 + kx;
#pragma unroll 4
      for (int c = 0; c < 64; c++) {
        float4 wa = *(const float4*)(wbase + (size_t)c * 128);
        const float* ib = ibase + c * 180;
        float iv[8];
#pragma unroll
        for (int k = 0; k < 8; k++) iv[k] = ib[k];
#pragma unroll
        for (int k = 0; k < 8; k++) {
          acc[k][0] = fmaf(iv[k], wa.x, acc[k][0]);
          acc[k][1] = fmaf(iv[k], wa.y, acc[k][1]);
          acc[k][2] = fmaf(iv[k], wa.z, acc[k][2]);
          acc[k][3] = fmaf(iv[k], wa.w, acc[k][3]);
        }
      }
    }
  }
  int oy = iy0 + py;
  if (oy < 35) {
#pragma unroll
    for (int k = 0; k < 8; k++) {
      int ox = ix0 + px0 + k;
      if (ox < 55) {
        float* op = out + ((size_t)(n * 35 + oy) * 55 + ox) * 128 + ob;
        float4 v0;
        v0.x = fmaxf(acc[k][0], 0.f); v0.y = fmaxf(acc[k][1], 0.f);
        v0.z = fmaxf(acc[k][2], 0.f); v0.w = fmaxf(acc[k][3], 0.f);
        ((float4*)op)[0] = v0;
      }
    }
  }
}

// ---------------- transpose a3 (8,246400) -> a3t (246400,8) ----------------
__global__ __launch_bounds__(256) void k_transpose_a3(const float* __restrict__ a3,
                                                      float* __restrict__ a3t) {
  int k = blockIdx.x * 256 + threadIdx.x;
  if (k >= 246400) return;
#pragma unroll
  for (int n = 0; n < 8; n++) a3t[(size_t)k * 8 + n] = a3[(size_t)n * 246400 + k];
}

// ---------------- dense1: (8,246400) @ (246400,256), split-K partials ----------------
__global__ __launch_bounds__(256) void k_dense1(const float* __restrict__ a3t,
    const float* __restrict__ wd1, float* __restrict__ part) {
  __shared__ float red[4][64][32];
  int c = blockIdx.x;
  int tid = threadIdx.x;
  int c4 = tid & 63;
  int ks = tid >> 6;
  int k0 = c * 256;
  int kn = 246400 - k0;
  if (kn > 256) kn = 256;
  float acc[8][4];
#pragma unroll
  for (int n = 0; n < 8; n++)
#pragma unroll
    for (int j = 0; j < 4; j++) acc[n][j] = 0.f;
  int kbeg = ks * 64;
  int kend = kbeg + 64;
  if (kend > kn) kend = kn;
#pragma unroll 1
  for (int kk = kbeg; kk < kend; kk++) {
    size_t row = (size_t)(k0 + kk);
    float4 wv = *(const float4*)(wd1 + row * 256 + c4 * 4);
    float4 xa = *(const float4*)(a3t + row * 8);
    float4 xb = *(const float4*)(a3t + row * 8 + 4);
    float xs[8] = {xa.x, xa.y, xa.z, xa.w, xb.x, xb.y, xb.z, xb.w};
#pragma unroll
    for (int n = 0; n < 8; n++) {
      acc[n][0] = fmaf(xs[n], wv.x, acc[n][0]);
      acc[n][1] = fmaf(xs[n], wv.y, acc[n][1]);
      acc[n][2] = fmaf(xs[n], wv.z, acc[n][2]);
      acc[n][3] = fmaf(xs[n], wv.w, acc[n][3]);
    }
  }
#pragma unroll
  for (int n = 0; n < 8; n++)
#pragma unroll
    for (int j = 0; j < 4; j++) red[ks][c4][n * 4 + j] = acc[n][j];
  __syncthreads();
  for (int o = tid; o < 2048; o += 256) {
    int col = o & 255, n = o >> 8;
    int cc = col >> 2, j = col & 3;
    float s = red[0][cc][n * 4 + j] + red[1][cc][n * 4 + j] +
              red[2][cc][n * 4 + j] + red[3][cc][n * 4 + j];
    part[(size_t)c * 2048 + n * 256 + col] = s;
  }
}

// ---------------- reduce1 stage A: 16 c-chunks x 2048 outputs, coalesced ----------------
__global__ __launch_bounds__(256) void k_reduce1a(const float* __restrict__ part,
    float* __restrict__ partr) {
  int bx = blockIdx.x;                       // 0..15 c-chunk
  int t = blockIdx.y * 256 + threadIdx.x;    // 0..2047
  int cbeg = bx * 61;
  int cend = cbeg + 61;
  if (cend > 963) cend = 963;
  float s = 0.f;
  for (int c = cbeg; c < cend; c++) s += part[(size_t)c * 2048 + t];
  partr[(size_t)bx * 2048 + t] = s;
}

__global__ __launch_bounds__(256) void k_reduce1b(const float* __restrict__ partr,
    const float* __restrict__ bd1, float* __restrict__ d1t) {
  int t = blockIdx.x * 256 + threadIdx.x;
  if (t >= 2048) return;
  float s = 0.f;
#pragma unroll
  for (int b = 0; b < 16; b++) s += partr[(size_t)b * 2048 + t];
  int n = t >> 8, j = t & 255;
  float v = s + bd1[j];
  d1t[j * 8 + n] = fmaxf(v, 0.f);  // ReLU; store transposed (256,8)
}

// ---------------- dense2 full-K fused: (8,256) @ (256,38400) + bias ----------------
__global__ __launch_bounds__(256) void k_dense2f(const float* __restrict__ d1t,
    const float* __restrict__ wd2, const float* __restrict__ bd2, float* __restrict__ d2) {
  __shared__ float red[4][64][32];
  int jb = blockIdx.x;  // 150
  int tid = threadIdx.x;
  int c4 = tid & 63;
  int ks = tid >> 6;
  int j0 = jb * 256 + c4 * 4;
  float acc[8][4];
#pragma unroll
  for (int n = 0; n < 8; n++)
#pragma unroll
    for (int j = 0; j < 4; j++) acc[n][j] = 0.f;
#pragma unroll 1
  for (int kk = 0; kk < 64; kk++) {
    int row = ks * 64 + kk;
    float4 wv = *(const float4*)(wd2 + (size_t)row * 38400 + j0);
    float4 xa = *(const float4*)(d1t + row * 8);
    float4 xb = *(const float4*)(d1t + row * 8 + 4);
    float xs[8] = {xa.x, xa.y, xa.z, xa.w, xb.x, xb.y, xb.z, xb.w};
#pragma unroll
    for (int n = 0; n < 8; n++) {
      acc[n][0] = fmaf(xs[n], wv.x, acc[n][0]);
      acc[n][1] = fmaf(xs[n], wv.y, acc[n][1]);
      acc[n][2] = fmaf(xs[n], wv.z, acc[n][2]);
      acc[n][3] = fmaf(xs[n], wv.w, acc[n][3]);
    }
  }
#pragma unroll
  for (int n = 0; n < 8; n++)
#pragma unroll
    for (int j = 0; j < 4; j++) red[ks][c4][n * 4 + j] = acc[n][j];
  __syncthreads();
  for (int o = tid; o < 2048; o += 256) {
    int col = o & 255, n = o >> 8;
    int cc = col >> 2, j = col & 3;
    float s = red[0][cc][n * 4 + j] + red[1][cc][n * 4 + j] +
              red[2][cc][n * 4 + j] + red[3][cc][n * 4 + j] + bd2[jb * 256 + col];
    d2[(size_t)n * 38400 + jb * 256 + col] = s;
  }
}

// ---------------- transform + keep-zero fused ----------------
__global__ __launch_bounds__(256) void k_transform(const float* __restrict__ d2,
    float* __restrict__ pred, float* __restrict__ boxd, float* __restrict__ keep_out) {
  int t = blockIdx.x * 256 + threadIdx.x;  // 0..115199
  if (t < 115200) keep_out[t] = 0.f;
  if (t >= 19200) return;
  int cell = t % 2400;
  int n = t / 2400;
  float gx = (float)(cell % 60), gy = (float)(cell / 60);
  const float* p = d2 + (size_t)t * 16;
  float o[16];
  o[0] = (sigmoidf_(p[0]) + gx) * 4.0f;
  o[1] = (sigmoidf_(p[1]) + gy) * 4.0f;
  o[2] = expf(p[2]) * 60.0f * 4.0f;
  o[3] = expf(p[3]) * 30.0f * 4.0f;
  o[4] = sigmoidf_(p[4]);
  o[5] = sigmoidf_(p[5]);
  o[6] = sigmoidf_(p[6]);
  o[7] = sigmoidf_(p[7]);
  o[8] = (p[8] + gx) * 4.0f;
  o[9] = (p[9] + gy) * 4.0f;
  o[10] = expf(p[10]) * 20.0f * 4.0f;
  o[11] = expf(p[11]) * 40.0f * 4.0f;
  o[12] = p[12];
  o[13] = sigmoidf_(p[13]);
  o[14] = sigmoidf_(p[14]);
  o[15] = sigmoidf_(p[15]);
  float* op = pred + (size_t)t * 16;
#pragma unroll
  for (int q = 0; q < 16; q++) op[q] = o[q];
#pragma unroll
  for (int h = 0; h < 2; h++) {
    int b = n * 4800 + h * 2400 + cell;
    float X = o[h * 8 + 0], Y = o[h * 8 + 1], W = o[h * 8 + 2], H = o[h * 8 + 3];
    float conf = o[h * 8 + 4];
    float c0 = o[h * 8 + 5], c1 = o[h * 8 + 6], c2 = o[h * 8 + 7];
    int cls = 0; float best = c0;
    if (c1 > best) { best = c1; cls = 1; }
    if (c2 > best) { best = c2; cls = 2; }
    float x1 = X - W / 2.0f, y1 = Y - H / 2.0f;
    float x2 = X + W / 2.0f, y2 = Y + H / 2.0f;
    float area = (x2 - x1 + 1.0f) * (y2 - y1 + 1.0f);
    float* bp2 = boxd + (size_t)b * 8;
    bp2[0] = x1; bp2[1] = y1; bp2[2] = x2; bp2[3] = y2;
    bp2[4] = area; bp2[5] = conf;
    ((int*)bp2)[6] = cls; bp2[7] = 0.f;
  }
}

// ---------------- NMS: one block per (image, class), fully LDS-resident ----------------
__global__ __launch_bounds__(256) void k_nms(const float* __restrict__ boxd,
    float* __restrict__ keep_out) {
  __shared__ unsigned long long key[8192];  // sort keys; low32 = orig idx
  __shared__ float4 sbox[4800];             // sorted x1,y1,x2,y2
  __shared__ unsigned avail[150];
  __shared__ int scnt;
  __shared__ int s_sel;
  int bid = blockIdx.x;  // 0..23
  int n = bid / 3, c = bid - n * 3;
  int tid = threadIdx.x;
  const float* bd = boxd + (size_t)n * 4800 * 8;
  if (tid == 0) scnt = 0;
  __syncthreads();

  for (int p = tid; p < 4800; p += 256) {
    const float* bp = bd + (size_t)p * 8;
    float conf = bp[5];
    int cls = ((const int*)bp)[6];
    if (conf > 0.5f && cls == c) {
      int slot = atomicAdd(&scnt, 1);
      unsigned u = __float_as_uint(conf);
      unsigned asc = (u & 0x80000000u) ? ~u : (u | 0x80000000u);
      key[slot] = (((unsigned long long)(~asc)) << 32) | (unsigned)p;
    }
  }
  __syncthreads();
  int V = scnt;
  if (V == 0) return;
  int Vp2 = 1;
  while (Vp2 < V) Vp2 <<= 1;
  for (int s = V + tid; s < Vp2; s += 256) key[s] = ~0ull;

  for (int k = 2; k <= Vp2; k <<= 1) {
    for (int j = k >> 1; j > 0; j >>= 1) {
      __syncthreads();
      int jm = j - 1;
      for (int t2 = tid; t2 < (Vp2 >> 1); t2 += 256) {
        int i = ((t2 & ~jm) << 1) | (t2 & jm);
        int q = i | j;
        bool up = ((i & k) == 0);
        unsigned long long a = key[i], b2 = key[q];
        if ((a > b2) == up) { key[i] = b2; key[q] = a; }
      }
    }
  }
  __syncthreads();

  for (int s = tid; s < V; s += 256) {
    unsigned p = (unsigned)(key[s] & 0xFFFFFFFFull);
    const float* bp = bd + (size_t)p * 8;
    float4 b4;
    b4.x = bp[0]; b4.y = bp[1]; b4.z = bp[2]; b4.w = bp[3];
    sbox[s] = b4;
  }
  for (int w = tid; w < 150; w += 256) {
    int rem = V - (w << 5);
    avail[w] = (rem >= 32) ? 0xFFFFFFFFu : (rem <= 0 ? 0u : ((1u << rem) - 1u));
  }
  __syncthreads();

  float* ko = keep_out + (size_t)bid * 4800;
  for (;;) {
    if (tid < 64) {
      int cand = 0x7FFFFFFF;
      for (int w = tid; w < 150; w += 64) {
        unsigned a = avail[w];
        if (a) {
          int c2 = (w << 5) + __ffs(a) - 1;
          if (c2 < cand) cand = c2;
        }
      }
      for (int off = 32; off > 0; off >>= 1) {
        int o = __shfl_xor(cand, off, 64);
        if (o < cand) cand = o;
      }
      if (tid == 0) s_sel = cand;
    }
    __syncthreads();
    int i = s_sel;
    if (i == 0x7FFFFFFF) break;
    float4 bi = sbox[i];
    float ai = (bi.z - bi.x + 1.0f) * (bi.w - bi.y + 1.0f);
    if (tid == 0) {
      ko[(unsigned)(key[i] & 0xFFFFFFFFull)] = 1.0f;
      avail[i >> 5] &= ~(1u << (i & 31));
    }
    __syncthreads();
    for (int j = i + 1 + tid; j < V; j += 256) {
      if (!((avail[j >> 5] >> (j & 31)) & 1u)) continue;
      float4 bj = sbox[j];
      float iw = fminf(bi.z, bj.z) - fmaxf(bi.x, bj.x) + 1.0f;
      float ih = fminf(bi.w, bj.w) - fmaxf(bi.y, bj.y) + 1.0f;
      iw = fmaxf(iw, 0.f);
      ih = fmaxf(ih, 0.f);
      float inter = iw * ih;
      float aj = (bj.z - bj.x + 1.0f) * (bj.w - bj.y + 1.0f);
      float iou = inter / (ai + aj - inter);
      if (iou >= 0.4f) atomicAnd(&avail[j >> 5], ~(1u << (j & 31)));
    }
    __syncthreads();
  }
}

extern "C" void kernel_launch(void* const* d_in, const int* in_sizes, int n_in,
                              void* d_out, int out_size, void* d_ws, size_t ws_size,
                              hipStream_t stream) {
  const float* img = (const float*)d_in[0];
  const float* w1 = (const float*)d_in[1];
  const float* b1 = (const float*)d_in[2];
  const float* w2 = (const float*)d_in[3];
  const float* b2 = (const float*)d_in[4];
  const float* w3 = (const float*)d_in[5];
  const float* b3 = (const float*)d_in[6];
  const float* wd1 = (const float*)d_in[7];
  const float* bd1 = (const float*)d_in[8];
  const float* wd2 = (const float*)d_in[9];
  const float* bd2 = (const float*)d_in[10];

  float* ws = (float*)d_ws;
  float* a3 = ws + 0;                 // 1,971,200
  float* a3t = ws + 1971200;          // 1,971,200
  float* pd1 = ws + 3942400;          // 963*2048 = 1,972,224
  float* partr = ws + 5914624;        // 16*2048 = 32,768
  float* d1t = ws + 5947392;          // 2048
  float* d2 = ws + 5949440;           // 307,200
  float* boxd = ws + 6256640;         // 307,200
  float* p1 = ws + 9324800;           // 8*77*117*32 = 2,306,304 pooled conv1
  float* p2 = ws + 16047104;          // 8*37*57*64 = 1,079,808 pooled conv2

  float* pred = (float*)d_out;
  float* keep = pred + 307200;

  k_conv1p<<<dim3(8, 10, 8), 256, 0, stream>>>(img, w1, b1, p1);
  k_conv2p<<<dim3(8, 10, 8), 128, 0, stream>>>(p1, w2, b2, p2);
  k_conv3<<<dim3(4, 5, 16), 256, 0, stream>>>(p2, w3, b3, a3);
  k_transpose_a3<<<(246400 + 255) / 256, 256, 0, stream>>>(a3, a3t);
  k_dense1<<<963, 256, 0, stream>>>(a3t, wd1, pd1);
  k_reduce1a<<<dim3(16, 8), 256, 0, stream>>>(pd1, partr);
  k_reduce1b<<<8, 256, 0, stream>>>(partr, bd1, d1t);
  k_dense2f<<<150, 256, 0, stream>>>(d1t, wd2, bd2, d2);
  k_transform<<<450, 256, 0, stream>>>(d2, pred, boxd, keep);
  k_nms<<<24, 256, 0, stream>>>(boxd, keep);
}